// Round 1
// baseline (4096.377 us; speedup 1.0000x reference)
//
#include <hip/hip_runtime.h>

#define H 64
#define N_STAY 200000
#define N_PAT  100000
#define N_EDGE 1000000

__device__ __forceinline__ float wave_sum(float v) {
  #pragma unroll
  for (int off = 32; off > 0; off >>= 1) v += __shfl_xor(v, off);
  return v;
}

// y = relu(x @ W + b), x: N x K, W: K x H, one wave per node (lane = out feature)
template<int K>
__global__ __launch_bounds__(256)
void proj_kernel(const float* __restrict__ x, const float* __restrict__ W,
                 const float* __restrict__ b, float* __restrict__ y, int N) {
  __shared__ float wlds[K * H];
  for (int i = threadIdx.x; i < K * H / 4; i += 256)
    ((float4*)wlds)[i] = ((const float4*)W)[i];
  __syncthreads();
  const int lane = threadIdx.x & 63;
  const int node = blockIdx.x * 4 + (threadIdx.x >> 6);
  if (node >= N) return;
  const float* xr = x + (size_t)node * K;
  float x0 = xr[lane];
  float x1 = (K > 64) ? xr[lane + 64] : 0.0f;
  float acc = b[lane];
  #pragma unroll
  for (int k = 0; k < K; ++k) {
    float xv = (k < 64) ? __shfl(x0, k) : __shfl(x1, k - 64);
    acc = fmaf(xv, wlds[k * H + lane], acc);
  }
  y[(size_t)node * H + lane] = fmaxf(acc, 0.0f);
}

// one wave per edge: lane = feature; coalesced 256B gather + 256B atomic burst
__global__ __launch_bounds__(256)
void scatter_kernel(const float* __restrict__ xsrc, const int* __restrict__ src,
                    const int* __restrict__ dst, float* __restrict__ sum,
                    float* __restrict__ cnt, int E) {
  const int w = (int)((blockIdx.x * 256 + threadIdx.x) >> 6);
  const int lane = threadIdx.x & 63;
  if (w >= E) return;
  const int s = src[w];
  const int d = dst[w];
  float v = xsrc[(size_t)s * H + lane];
  atomicAdd(&sum[(size_t)d * H + lane], v);
  if (lane == 0) atomicAdd(&cnt[d], 1.0f);
}

// fused: agg = sum/max(cnt,1); y = l2norm(agg@Wl + bl + x@Wr); relu; LN. One wave per node.
// out may alias sum (row-local read-then-write).
__global__ __launch_bounds__(256)
void sage_one_kernel(const float* __restrict__ sum, const float* __restrict__ cnt,
                     const float* __restrict__ xdst,
                     const float* __restrict__ Wl, const float* __restrict__ bl,
                     const float* __restrict__ Wr,
                     const float* __restrict__ g, const float* __restrict__ bb,
                     float* __restrict__ out, int N) {
  __shared__ float lds[2 * H * H];
  float* wl = lds;
  float* wr = lds + H * H;
  for (int i = threadIdx.x; i < H * H / 4; i += 256) {
    ((float4*)wl)[i] = ((const float4*)Wl)[i];
    ((float4*)wr)[i] = ((const float4*)Wr)[i];
  }
  __syncthreads();
  const int lane = threadIdx.x & 63;
  const int node = blockIdx.x * 4 + (threadIdx.x >> 6);
  if (node >= N) return;
  const float inv = 1.0f / fmaxf(cnt[node], 1.0f);
  float a = sum[(size_t)node * H + lane] * inv;
  float xv = xdst[(size_t)node * H + lane];
  float y = bl[lane];
  #pragma unroll
  for (int k = 0; k < H; ++k) {
    float ak = __shfl(a, k);
    float xk = __shfl(xv, k);
    y = fmaf(ak, wl[k * H + lane], y);
    y = fmaf(xk, wr[k * H + lane], y);
  }
  float n2 = wave_sum(y * y);
  y = y / fmaxf(sqrtf(n2), 1e-12f);
  y = fmaxf(y, 0.0f);
  float m = wave_sum(y) * (1.0f / H);
  float d = y - m;
  float var = wave_sum(d * d) * (1.0f / H);
  y = d * rsqrtf(var + 1e-5f) * g[lane] + bb[lane];
  out[(size_t)node * H + lane] = y;
}

// stays: two edge types -> two separate SAGE outputs, averaged, relu, LN.
__global__ __launch_bounds__(256)
void sage_two_kernel(const float* __restrict__ sum2, const float* __restrict__ cnt2,
                     const float* __restrict__ sum3, const float* __restrict__ cnt3,
                     const float* __restrict__ xdst,
                     const float* __restrict__ Wl2, const float* __restrict__ bl2,
                     const float* __restrict__ Wr2,
                     const float* __restrict__ Wl3, const float* __restrict__ bl3,
                     const float* __restrict__ Wr3,
                     const float* __restrict__ g, const float* __restrict__ bb,
                     float* __restrict__ out, int N) {
  __shared__ float lds[4 * H * H];  // 64 KB
  float* wl2 = lds;
  float* wl3 = lds + H * H;
  float* wr2 = lds + 2 * H * H;
  float* wr3 = lds + 3 * H * H;
  for (int i = threadIdx.x; i < H * H / 4; i += 256) {
    ((float4*)wl2)[i] = ((const float4*)Wl2)[i];
    ((float4*)wl3)[i] = ((const float4*)Wl3)[i];
    ((float4*)wr2)[i] = ((const float4*)Wr2)[i];
    ((float4*)wr3)[i] = ((const float4*)Wr3)[i];
  }
  __syncthreads();
  const int lane = threadIdx.x & 63;
  const int node = blockIdx.x * 4 + (threadIdx.x >> 6);
  if (node >= N) return;
  const float inv2 = 1.0f / fmaxf(cnt2[node], 1.0f);
  const float inv3 = 1.0f / fmaxf(cnt3[node], 1.0f);
  float a2 = sum2[(size_t)node * H + lane] * inv2;
  float a3 = sum3[(size_t)node * H + lane] * inv3;
  float xv = xdst[(size_t)node * H + lane];
  float y2 = bl2[lane];
  float y3 = bl3[lane];
  #pragma unroll
  for (int k = 0; k < H; ++k) {
    float s2 = __shfl(a2, k);
    float s3 = __shfl(a3, k);
    float sx = __shfl(xv, k);
    y2 = fmaf(s2, wl2[k * H + lane], y2);
    y2 = fmaf(sx, wr2[k * H + lane], y2);
    y3 = fmaf(s3, wl3[k * H + lane], y3);
    y3 = fmaf(sx, wr3[k * H + lane], y3);
  }
  float n2a = wave_sum(y2 * y2);
  float n3a = wave_sum(y3 * y3);
  y2 = y2 / fmaxf(sqrtf(n2a), 1e-12f);
  y3 = y3 / fmaxf(sqrtf(n3a), 1e-12f);
  float y = 0.5f * (y2 + y3);
  y = fmaxf(y, 0.0f);
  float m = wave_sum(y) * (1.0f / H);
  float d = y - m;
  float var = wave_sum(d * d) * (1.0f / H);
  y = d * rsqrtf(var + 1e-5f) * g[lane] + bb[lane];
  out[(size_t)node * H + lane] = y;
}

__global__ __launch_bounds__(256)
void reg_kernel(const float* __restrict__ hs, const float* __restrict__ Wreg,
                const float* __restrict__ breg, float* __restrict__ out, int N) {
  const int lane = threadIdx.x & 63;
  const int node = blockIdx.x * 4 + (threadIdx.x >> 6);
  if (node >= N) return;
  float t = hs[(size_t)node * H + lane] * Wreg[lane];
  t = wave_sum(t);
  if (lane == 0) out[node] = t + breg[0];
}

extern "C" void kernel_launch(void* const* d_in, const int* in_sizes, int n_in,
                              void* d_out, int out_size, void* d_ws, size_t ws_size,
                              hipStream_t stream) {
  const float* x_stay  = (const float*)d_in[0];
  const float* x_pat   = (const float*)d_in[1];
  const float* Wp_stay = (const float*)d_in[2];
  const float* bp_stay = (const float*)d_in[3];
  const float* Wp_pat  = (const float*)d_in[4];
  const float* bp_pat  = (const float*)d_in[5];
  const float* Wl      = (const float*)d_in[6];
  const float* bl      = (const float*)d_in[7];
  const float* Wr      = (const float*)d_in[8];
  const float* ln_g    = (const float*)d_in[9];
  const float* ln_b    = (const float*)d_in[10];
  const float* Wreg    = (const float*)d_in[11];
  const float* breg    = (const float*)d_in[12];
  const int* e1s = (const int*)d_in[13];
  const int* e1d = (const int*)d_in[14];
  const int* e2s = (const int*)d_in[15];
  const int* e2d = (const int*)d_in[16];
  const int* e3s = (const int*)d_in[17];
  const int* e3d = (const int*)d_in[18];
  float* out = (float*)d_out;

  const size_t S = (size_t)N_STAY * H;  // 12.8M floats
  const size_t P = (size_t)N_PAT * H;   // 6.4M floats
  float* ws = (float*)d_ws;
  float* bufA  = ws;            // stay-sized
  float* bufB  = bufA + S;      // stay-sized
  float* bufC  = bufB + S;      // stay-sized
  float* bufP0 = bufC + S;      // pat-sized
  float* bufP1 = bufP0 + P;     // pat-sized
  float* cnt2  = bufP1 + P;     // N_STAY
  float* cnt3  = cnt2 + N_STAY; // N_STAY
  float* cnt1  = cnt3 + N_STAY; // N_PAT

  const int SCAT_BLOCKS = N_EDGE / 4;  // one wave per edge

  // input projections + relu
  proj_kernel<128><<<(N_STAY + 3) / 4, 256, 0, stream>>>(x_stay, Wp_stay, bp_stay, bufA, N_STAY);
  proj_kernel<64><<<(N_PAT + 3) / 4, 256, 0, stream>>>(x_pat, Wp_pat, bp_pat, bufP0, N_PAT);

  float* hs = bufA;
  float* hp = bufP0;
  float* freeS1 = bufB;  // free stay-sized buffers for this layer's sums
  float* freeS2 = bufC;
  float* freeP  = bufP1;

  for (int l = 0; l < 2; ++l) {
    float* sum2 = freeS1;
    float* sum3 = freeS2;
    float* sum1 = freeP;
    hipMemsetAsync(sum2, 0, S * sizeof(float), stream);
    hipMemsetAsync(sum3, 0, S * sizeof(float), stream);
    hipMemsetAsync(sum1, 0, P * sizeof(float), stream);
    hipMemsetAsync(cnt2, 0, N_STAY * sizeof(float), stream);
    hipMemsetAsync(cnt3, 0, N_STAY * sizeof(float), stream);
    hipMemsetAsync(cnt1, 0, N_PAT * sizeof(float), stream);

    // scatter-sums (mean numerators) + in-degree counts
    scatter_kernel<<<SCAT_BLOCKS, 256, 0, stream>>>(hs, e1s, e1d, sum1, cnt1, N_EDGE);
    scatter_kernel<<<SCAT_BLOCKS, 256, 0, stream>>>(hp, e2s, e2d, sum2, cnt2, N_EDGE);
    scatter_kernel<<<SCAT_BLOCKS, 256, 0, stream>>>(hs, e3s, e3d, sum3, cnt3, N_EDGE);

    const float* Wl0 = Wl + (size_t)(l * 3 + 0) * H * H;
    const float* Wl1 = Wl + (size_t)(l * 3 + 1) * H * H;
    const float* Wl2 = Wl + (size_t)(l * 3 + 2) * H * H;
    const float* Wr0 = Wr + (size_t)(l * 3 + 0) * H * H;
    const float* Wr1 = Wr + (size_t)(l * 3 + 1) * H * H;
    const float* Wr2 = Wr + (size_t)(l * 3 + 2) * H * H;
    const float* bl0 = bl + (size_t)(l * 3 + 0) * H;
    const float* bl1 = bl + (size_t)(l * 3 + 1) * H;
    const float* bl2 = bl + (size_t)(l * 3 + 2) * H;
    const float* g  = ln_g + (size_t)l * H;
    const float* bb = ln_b + (size_t)l * H;

    // patients: o1 -> relu -> LN (in-place into sum1)
    sage_one_kernel<<<(N_PAT + 3) / 4, 256, 0, stream>>>(
        sum1, cnt1, hp, Wl0, bl0, Wr0, g, bb, sum1, N_PAT);
    // stays: 0.5*(o2+o3) -> relu -> LN (in-place into sum2)
    sage_two_kernel<<<(N_STAY + 3) / 4, 256, 0, stream>>>(
        sum2, cnt2, sum3, cnt3, hs, Wl1, bl1, Wr1, Wl2, bl2, Wr2, g, bb, sum2, N_STAY);

    // rotate buffers
    float* oldHs = hs;
    float* oldHp = hp;
    hs = sum2;
    hp = sum1;
    freeS1 = oldHs;
    freeS2 = sum3;
    freeP = oldHp;
  }

  reg_kernel<<<(N_STAY + 3) / 4, 256, 0, stream>>>(hs, Wreg, breg, out, N_STAY);
}

// Round 2
// 2741.090 us; speedup vs baseline: 1.4944x; 1.4944x over previous
//
#include <hip/hip_runtime.h>

#define H 64
#define N_STAY 200000
#define N_PAT  100000
#define N_EDGE 1000000

__device__ __forceinline__ float wave_sum(float v) {
  #pragma unroll
  for (int off = 32; off > 0; off >>= 1) v += __shfl_xor(v, off);
  return v;
}

// ---------------- dense kernels: thread-per-node, weights via scalar loads ----

// y = relu(x @ W + b). One thread per node; acc[j] in VGPRs; W read at
// wave-uniform addresses -> s_load (SMEM pipe), x row per-thread float4.
template<int K>
__global__ __launch_bounds__(256)
void proj_dense(const float* __restrict__ x, const float* __restrict__ W,
                const float* __restrict__ b, float* __restrict__ y, int N) {
  const int n = blockIdx.x * 256 + threadIdx.x;
  if (n >= N) return;
  float acc[H];
  #pragma unroll
  for (int j = 0; j < H; ++j) acc[j] = b[j];
  const float4* xr = (const float4*)(x + (size_t)n * K);
  float4 xn = xr[0];
  for (int kb = 0; kb < K / 4; ++kb) {
    float4 xv = xn;
    if (kb + 1 < K / 4) xn = xr[kb + 1];
    const float xa[4] = {xv.x, xv.y, xv.z, xv.w};
    #pragma unroll
    for (int dk = 0; dk < 4; ++dk) {
      const float4* wr = (const float4*)(W + (size_t)(kb * 4 + dk) * H);
      #pragma unroll
      for (int jc = 0; jc < H / 4; ++jc) {
        float4 w = wr[jc];
        acc[jc * 4 + 0] = fmaf(xa[dk], w.x, acc[jc * 4 + 0]);
        acc[jc * 4 + 1] = fmaf(xa[dk], w.y, acc[jc * 4 + 1]);
        acc[jc * 4 + 2] = fmaf(xa[dk], w.z, acc[jc * 4 + 2]);
        acc[jc * 4 + 3] = fmaf(xa[dk], w.w, acc[jc * 4 + 3]);
      }
    }
  }
  float* yr = y + (size_t)n * H;
  #pragma unroll
  for (int jc = 0; jc < H / 4; ++jc) {
    float4 o;
    o.x = fmaxf(acc[jc * 4 + 0], 0.0f);
    o.y = fmaxf(acc[jc * 4 + 1], 0.0f);
    o.z = fmaxf(acc[jc * 4 + 2], 0.0f);
    o.w = fmaxf(acc[jc * 4 + 3], 0.0f);
    ((float4*)yr)[jc] = o;
  }
}

// patients: y = LN(relu(l2norm((sum/cnt)@W1 + b1 + x@W2))). out may alias sum.
__global__ __launch_bounds__(256)
void sage_one_dense(const float* __restrict__ sum, const float* __restrict__ cnt,
                    const float* __restrict__ x,
                    const float* __restrict__ W1, const float* __restrict__ b1,
                    const float* __restrict__ W2,
                    const float* __restrict__ g, const float* __restrict__ bb,
                    float* __restrict__ out, int N) {
  const int n = blockIdx.x * 256 + threadIdx.x;
  if (n >= N) return;
  const float inv = 1.0f / fmaxf(cnt[n], 1.0f);
  float acc[H];
  #pragma unroll
  for (int j = 0; j < H; ++j) acc[j] = b1[j];
  const float4* a4 = (const float4*)(sum + (size_t)n * H);
  const float4* x4 = (const float4*)(x + (size_t)n * H);
  float4 an = a4[0], xn = x4[0];
  for (int kb = 0; kb < H / 4; ++kb) {
    float4 av = an, xv = xn;
    if (kb + 1 < H / 4) { an = a4[kb + 1]; xn = x4[kb + 1]; }
    const float aa[4] = {av.x * inv, av.y * inv, av.z * inv, av.w * inv};
    const float xa[4] = {xv.x, xv.y, xv.z, xv.w};
    #pragma unroll
    for (int dk = 0; dk < 4; ++dk) {
      const float4* w1r = (const float4*)(W1 + (size_t)(kb * 4 + dk) * H);
      const float4* w2r = (const float4*)(W2 + (size_t)(kb * 4 + dk) * H);
      #pragma unroll
      for (int jc = 0; jc < H / 4; ++jc) {
        float4 w1 = w1r[jc], w2 = w2r[jc];
        acc[jc * 4 + 0] = fmaf(aa[dk], w1.x, fmaf(xa[dk], w2.x, acc[jc * 4 + 0]));
        acc[jc * 4 + 1] = fmaf(aa[dk], w1.y, fmaf(xa[dk], w2.y, acc[jc * 4 + 1]));
        acc[jc * 4 + 2] = fmaf(aa[dk], w1.z, fmaf(xa[dk], w2.z, acc[jc * 4 + 2]));
        acc[jc * 4 + 3] = fmaf(aa[dk], w1.w, fmaf(xa[dk], w2.w, acc[jc * 4 + 3]));
      }
    }
  }
  // epilogue entirely in registers
  float n2 = 0.0f;
  #pragma unroll
  for (int j = 0; j < H; ++j) n2 = fmaf(acc[j], acc[j], n2);
  const float r = 1.0f / fmaxf(sqrtf(n2), 1e-12f);
  float m = 0.0f;
  #pragma unroll
  for (int j = 0; j < H; ++j) { acc[j] = fmaxf(acc[j] * r, 0.0f); m += acc[j]; }
  m *= (1.0f / H);
  float var = 0.0f;
  #pragma unroll
  for (int j = 0; j < H; ++j) { float d = acc[j] - m; var = fmaf(d, d, var); }
  const float s = rsqrtf(var * (1.0f / H) + 1e-5f);
  float* orow = out + (size_t)n * H;
  #pragma unroll
  for (int jc = 0; jc < H / 4; ++jc) {
    float4 o;
    o.x = (acc[jc * 4 + 0] - m) * s * g[jc * 4 + 0] + bb[jc * 4 + 0];
    o.y = (acc[jc * 4 + 1] - m) * s * g[jc * 4 + 1] + bb[jc * 4 + 1];
    o.z = (acc[jc * 4 + 2] - m) * s * g[jc * 4 + 2] + bb[jc * 4 + 2];
    o.w = (acc[jc * 4 + 3] - m) * s * g[jc * 4 + 3] + bb[jc * 4 + 3];
    ((float4*)orow)[jc] = o;
  }
}

// stays: y2 = l2norm((s2/c2)@W1 + b1 + x@Wr1); y3 = l2norm((s3/c3)@W3 + b3 + x@Wr3)
// out = LN(relu(0.5*(y2+y3))). out may alias sum2.
__global__ __launch_bounds__(256)
void sage_two_dense(const float* __restrict__ sum2, const float* __restrict__ cnt2,
                    const float* __restrict__ sum3, const float* __restrict__ cnt3,
                    const float* __restrict__ x,
                    const float* __restrict__ Wl2, const float* __restrict__ bl2,
                    const float* __restrict__ Wr2,
                    const float* __restrict__ Wl3, const float* __restrict__ bl3,
                    const float* __restrict__ Wr3,
                    const float* __restrict__ g, const float* __restrict__ bb,
                    float* __restrict__ out, int N) {
  const int n = blockIdx.x * 256 + threadIdx.x;
  if (n >= N) return;
  const float inv2 = 1.0f / fmaxf(cnt2[n], 1.0f);
  const float inv3 = 1.0f / fmaxf(cnt3[n], 1.0f);
  float acc2[H], acc3[H];
  #pragma unroll
  for (int j = 0; j < H; ++j) { acc2[j] = bl2[j]; acc3[j] = bl3[j]; }
  const float4* a2r = (const float4*)(sum2 + (size_t)n * H);
  const float4* a3r = (const float4*)(sum3 + (size_t)n * H);
  const float4* x4r = (const float4*)(x + (size_t)n * H);
  float4 a2n = a2r[0], a3n = a3r[0], xn = x4r[0];
  for (int kb = 0; kb < H / 4; ++kb) {
    float4 a2v = a2n, a3v = a3n, xv = xn;
    if (kb + 1 < H / 4) { a2n = a2r[kb + 1]; a3n = a3r[kb + 1]; xn = x4r[kb + 1]; }
    const float a2a[4] = {a2v.x * inv2, a2v.y * inv2, a2v.z * inv2, a2v.w * inv2};
    const float a3a[4] = {a3v.x * inv3, a3v.y * inv3, a3v.z * inv3, a3v.w * inv3};
    const float xa[4] = {xv.x, xv.y, xv.z, xv.w};
    #pragma unroll
    for (int dk = 0; dk < 4; ++dk) {
      const size_t ko = (size_t)(kb * 4 + dk) * H;
      const float4* w2l = (const float4*)(Wl2 + ko);
      const float4* w2r = (const float4*)(Wr2 + ko);
      const float4* w3l = (const float4*)(Wl3 + ko);
      const float4* w3r = (const float4*)(Wr3 + ko);
      #pragma unroll
      for (int jc = 0; jc < H / 4; ++jc) {
        float4 wa = w2l[jc], wb = w2r[jc], wc = w3l[jc], wd = w3r[jc];
        acc2[jc * 4 + 0] = fmaf(a2a[dk], wa.x, fmaf(xa[dk], wb.x, acc2[jc * 4 + 0]));
        acc2[jc * 4 + 1] = fmaf(a2a[dk], wa.y, fmaf(xa[dk], wb.y, acc2[jc * 4 + 1]));
        acc2[jc * 4 + 2] = fmaf(a2a[dk], wa.z, fmaf(xa[dk], wb.z, acc2[jc * 4 + 2]));
        acc2[jc * 4 + 3] = fmaf(a2a[dk], wa.w, fmaf(xa[dk], wb.w, acc2[jc * 4 + 3]));
        acc3[jc * 4 + 0] = fmaf(a3a[dk], wc.x, fmaf(xa[dk], wd.x, acc3[jc * 4 + 0]));
        acc3[jc * 4 + 1] = fmaf(a3a[dk], wc.y, fmaf(xa[dk], wd.y, acc3[jc * 4 + 1]));
        acc3[jc * 4 + 2] = fmaf(a3a[dk], wc.z, fmaf(xa[dk], wd.z, acc3[jc * 4 + 2]));
        acc3[jc * 4 + 3] = fmaf(a3a[dk], wc.w, fmaf(xa[dk], wd.w, acc3[jc * 4 + 3]));
      }
    }
  }
  float n2 = 0.0f, n3 = 0.0f;
  #pragma unroll
  for (int j = 0; j < H; ++j) {
    n2 = fmaf(acc2[j], acc2[j], n2);
    n3 = fmaf(acc3[j], acc3[j], n3);
  }
  const float r2 = 0.5f / fmaxf(sqrtf(n2), 1e-12f);  // fold the 0.5 avg
  const float r3 = 0.5f / fmaxf(sqrtf(n3), 1e-12f);
  float m = 0.0f;
  #pragma unroll
  for (int j = 0; j < H; ++j) {
    float y = fmaxf(fmaf(acc2[j], r2, acc3[j] * r3), 0.0f);
    acc2[j] = y;
    m += y;
  }
  m *= (1.0f / H);
  float var = 0.0f;
  #pragma unroll
  for (int j = 0; j < H; ++j) { float d = acc2[j] - m; var = fmaf(d, d, var); }
  const float s = rsqrtf(var * (1.0f / H) + 1e-5f);
  float* orow = out + (size_t)n * H;
  #pragma unroll
  for (int jc = 0; jc < H / 4; ++jc) {
    float4 o;
    o.x = (acc2[jc * 4 + 0] - m) * s * g[jc * 4 + 0] + bb[jc * 4 + 0];
    o.y = (acc2[jc * 4 + 1] - m) * s * g[jc * 4 + 1] + bb[jc * 4 + 1];
    o.z = (acc2[jc * 4 + 2] - m) * s * g[jc * 4 + 2] + bb[jc * 4 + 2];
    o.w = (acc2[jc * 4 + 3] - m) * s * g[jc * 4 + 3] + bb[jc * 4 + 3];
    ((float4*)orow)[jc] = o;
  }
}

// ---------------- scatter (unchanged this round; measuring) ------------------

__global__ __launch_bounds__(256)
void scatter_kernel(const float* __restrict__ xsrc, const int* __restrict__ src,
                    const int* __restrict__ dst, float* __restrict__ sum,
                    float* __restrict__ cnt, int E) {
  const int w = (int)((blockIdx.x * 256 + threadIdx.x) >> 6);
  const int lane = threadIdx.x & 63;
  if (w >= E) return;
  const int s = src[w];
  const int d = dst[w];
  float v = xsrc[(size_t)s * H + lane];
  atomicAdd(&sum[(size_t)d * H + lane], v);
  if (lane == 0) atomicAdd(&cnt[d], 1.0f);
}

__global__ __launch_bounds__(256)
void reg_kernel(const float* __restrict__ hs, const float* __restrict__ Wreg,
                const float* __restrict__ breg, float* __restrict__ out, int N) {
  const int lane = threadIdx.x & 63;
  const int node = blockIdx.x * 4 + (threadIdx.x >> 6);
  if (node >= N) return;
  float t = hs[(size_t)node * H + lane] * Wreg[lane];
  t = wave_sum(t);
  if (lane == 0) out[node] = t + breg[0];
}

extern "C" void kernel_launch(void* const* d_in, const int* in_sizes, int n_in,
                              void* d_out, int out_size, void* d_ws, size_t ws_size,
                              hipStream_t stream) {
  const float* x_stay  = (const float*)d_in[0];
  const float* x_pat   = (const float*)d_in[1];
  const float* Wp_stay = (const float*)d_in[2];
  const float* bp_stay = (const float*)d_in[3];
  const float* Wp_pat  = (const float*)d_in[4];
  const float* bp_pat  = (const float*)d_in[5];
  const float* Wl      = (const float*)d_in[6];
  const float* bl      = (const float*)d_in[7];
  const float* Wr      = (const float*)d_in[8];
  const float* ln_g    = (const float*)d_in[9];
  const float* ln_b    = (const float*)d_in[10];
  const float* Wreg    = (const float*)d_in[11];
  const float* breg    = (const float*)d_in[12];
  const int* e1s = (const int*)d_in[13];
  const int* e1d = (const int*)d_in[14];
  const int* e2s = (const int*)d_in[15];
  const int* e2d = (const int*)d_in[16];
  const int* e3s = (const int*)d_in[17];
  const int* e3d = (const int*)d_in[18];
  float* out = (float*)d_out;

  const size_t S = (size_t)N_STAY * H;
  const size_t P = (size_t)N_PAT * H;
  float* ws = (float*)d_ws;
  float* bufA  = ws;            // stay-sized
  float* bufB  = bufA + S;      // stay-sized
  float* bufC  = bufB + S;      // stay-sized
  float* bufP0 = bufC + S;      // pat-sized
  float* bufP1 = bufP0 + P;     // pat-sized
  float* cnt2  = bufP1 + P;     // N_STAY
  float* cnt3  = cnt2 + N_STAY; // N_STAY
  float* cnt1  = cnt3 + N_STAY; // N_PAT

  const int SCAT_BLOCKS = N_EDGE / 4;

  proj_dense<128><<<(N_STAY + 255) / 256, 256, 0, stream>>>(x_stay, Wp_stay, bp_stay, bufA, N_STAY);
  proj_dense<64><<<(N_PAT + 255) / 256, 256, 0, stream>>>(x_pat, Wp_pat, bp_pat, bufP0, N_PAT);

  float* hs = bufA;
  float* hp = bufP0;
  float* freeS1 = bufB;
  float* freeS2 = bufC;
  float* freeP  = bufP1;

  for (int l = 0; l < 2; ++l) {
    float* sum2 = freeS1;
    float* sum3 = freeS2;
    float* sum1 = freeP;
    hipMemsetAsync(sum2, 0, S * sizeof(float), stream);
    hipMemsetAsync(sum3, 0, S * sizeof(float), stream);
    hipMemsetAsync(sum1, 0, P * sizeof(float), stream);
    hipMemsetAsync(cnt2, 0, N_STAY * sizeof(float), stream);
    hipMemsetAsync(cnt3, 0, N_STAY * sizeof(float), stream);
    hipMemsetAsync(cnt1, 0, N_PAT * sizeof(float), stream);

    scatter_kernel<<<SCAT_BLOCKS, 256, 0, stream>>>(hs, e1s, e1d, sum1, cnt1, N_EDGE);
    scatter_kernel<<<SCAT_BLOCKS, 256, 0, stream>>>(hp, e2s, e2d, sum2, cnt2, N_EDGE);
    scatter_kernel<<<SCAT_BLOCKS, 256, 0, stream>>>(hs, e3s, e3d, sum3, cnt3, N_EDGE);

    const float* Wl0 = Wl + (size_t)(l * 3 + 0) * H * H;
    const float* Wl1 = Wl + (size_t)(l * 3 + 1) * H * H;
    const float* Wl2p = Wl + (size_t)(l * 3 + 2) * H * H;
    const float* Wr0 = Wr + (size_t)(l * 3 + 0) * H * H;
    const float* Wr1 = Wr + (size_t)(l * 3 + 1) * H * H;
    const float* Wr2p = Wr + (size_t)(l * 3 + 2) * H * H;
    const float* bl0 = bl + (size_t)(l * 3 + 0) * H;
    const float* bl1 = bl + (size_t)(l * 3 + 1) * H;
    const float* bl2p = bl + (size_t)(l * 3 + 2) * H;
    const float* g  = ln_g + (size_t)l * H;
    const float* bb = ln_b + (size_t)l * H;

    sage_one_dense<<<(N_PAT + 255) / 256, 256, 0, stream>>>(
        sum1, cnt1, hp, Wl0, bl0, Wr0, g, bb, sum1, N_PAT);
    sage_two_dense<<<(N_STAY + 255) / 256, 256, 0, stream>>>(
        sum2, cnt2, sum3, cnt3, hs, Wl1, bl1, Wr1, Wl2p, bl2p, Wr2p, g, bb, sum2, N_STAY);

    float* oldHs = hs;
    float* oldHp = hp;
    hs = sum2;
    hp = sum1;
    freeS1 = oldHs;
    freeS2 = sum3;
    freeP = oldHp;
  }

  reg_kernel<<<(N_STAY + 3) / 4, 256, 0, stream>>>(hs, Wreg, breg, out, N_STAY);
}

// Round 3
// 1969.042 us; speedup vs baseline: 2.0804x; 1.3921x over previous
//
#include <hip/hip_runtime.h>

#define H 64
#define N_STAY 200000
#define N_PAT  100000
#define N_EDGE 1000000
#define SCAN_CHUNK 4096  // 256 threads * 16 elems

typedef unsigned short ushort_t;

__device__ __forceinline__ float wave_sum(float v) {
  #pragma unroll
  for (int off = 32; off > 0; off >>= 1) v += __shfl_xor(v, off);
  return v;
}

__device__ __forceinline__ float bf2f(ushort_t u) {
  union { unsigned int i; float f; } c;
  c.i = ((unsigned int)u) << 16;
  return c.f;
}
__device__ __forceinline__ unsigned int f2bf_bits(float f) {
  union { float v; unsigned int i; } c; c.v = f;
  unsigned int r = c.i + 0x7fffu + ((c.i >> 16) & 1u);  // RNE
  return r >> 16;
}
__device__ __forceinline__ unsigned int pack2(float lo, float hi) {
  return f2bf_bits(lo) | (f2bf_bits(hi) << 16);
}
__device__ __forceinline__ void unpack8(uint4 q, float* f) {
  union { unsigned int i; float v; } c;
  c.i = q.x << 16;          f[0] = c.v;
  c.i = q.x & 0xffff0000u;  f[1] = c.v;
  c.i = q.y << 16;          f[2] = c.v;
  c.i = q.y & 0xffff0000u;  f[3] = c.v;
  c.i = q.z << 16;          f[4] = c.v;
  c.i = q.z & 0xffff0000u;  f[5] = c.v;
  c.i = q.w << 16;          f[6] = c.v;
  c.i = q.w & 0xffff0000u;  f[7] = c.v;
}

// ---------------- CSR build --------------------------------------------------

__global__ __launch_bounds__(256)
void hist_kernel(const int* __restrict__ dst, int E, int* __restrict__ hist) {
  int e = blockIdx.x * 256 + threadIdx.x;
  if (e < E) atomicAdd(&hist[dst[e]], 1);
}

__global__ __launch_bounds__(256)
void scan_block_totals(const int* __restrict__ in, int n, int* __restrict__ partials) {
  int base = blockIdx.x * SCAN_CHUNK + threadIdx.x * 16;
  int s = 0;
  #pragma unroll
  for (int i = 0; i < 16; ++i) { int idx = base + i; if (idx < n) s += in[idx]; }
  #pragma unroll
  for (int off = 32; off > 0; off >>= 1) s += __shfl_xor(s, off);
  __shared__ int wsum[4];
  if ((threadIdx.x & 63) == 0) wsum[threadIdx.x >> 6] = s;
  __syncthreads();
  if (threadIdx.x == 0) partials[blockIdx.x] = wsum[0] + wsum[1] + wsum[2] + wsum[3];
}

__global__ __launch_bounds__(64)
void scan_partials(int* __restrict__ partials, int np) {
  int lane = threadIdx.x;
  int orig = (lane < np) ? partials[lane] : 0;
  int v = orig;
  #pragma unroll
  for (int off = 1; off < 64; off <<= 1) {
    int t = __shfl_up(v, off);
    if (lane >= off) v += t;
  }
  if (lane < np) partials[lane] = v - orig;  // exclusive
}

// writes exclusive-scan to off[] AND cur[] (cur may alias in: per-thread read-then-write)
__global__ __launch_bounds__(256)
void scan_final(const int* __restrict__ in, int n, const int* __restrict__ partials,
                int* __restrict__ off, int* __restrict__ cur, int total) {
  int b = blockIdx.x, tid = threadIdx.x;
  int base = b * SCAN_CHUNK + tid * 16;
  int vals[16]; int s = 0;
  #pragma unroll
  for (int i = 0; i < 16; ++i) {
    int idx = base + i;
    vals[i] = (idx < n) ? in[idx] : 0;
    s += vals[i];
  }
  int lane = tid & 63, w = tid >> 6;
  int incl = s;
  #pragma unroll
  for (int o = 1; o < 64; o <<= 1) {
    int t = __shfl_up(incl, o);
    if (lane >= o) incl += t;
  }
  __shared__ int wtot[4];
  if (lane == 63) wtot[w] = incl;
  __syncthreads();
  int wbase = 0;
  for (int i = 0; i < w; ++i) wbase += wtot[i];
  int run = partials[b] + wbase + incl - s;  // exclusive prefix for this thread
  #pragma unroll
  for (int i = 0; i < 16; ++i) {
    int idx = base + i;
    if (idx < n) { off[idx] = run; cur[idx] = run; run += vals[i]; }
  }
  if (b == 0 && tid == 0) off[n] = total;
}

__global__ __launch_bounds__(256)
void reorder_kernel(const int* __restrict__ src, const int* __restrict__ dst, int E,
                    int* __restrict__ cur, int* __restrict__ csr) {
  int e = blockIdx.x * 256 + threadIdx.x;
  if (e >= E) return;
  int d = dst[e];
  int pos = atomicAdd(&cur[d], 1);
  csr[pos] = src[e];
}

// ---------------- aggregation: wave per dst node, lane = feature -------------

__global__ __launch_bounds__(256)
void agg_kernel(const ushort_t* __restrict__ x, const int* __restrict__ off,
                const int* __restrict__ csr, ushort_t* __restrict__ agg, int N) {
  const int node = (int)((blockIdx.x * 256 + threadIdx.x) >> 6);
  const int lane = threadIdx.x & 63;
  if (node >= N) return;
  const int o0 = off[node], o1 = off[node + 1];
  float acc = 0.0f;
  for (int i = o0; i < o1; ++i) {
    int s = csr[i];
    acc += bf2f(x[(size_t)s * H + lane]);
  }
  float mean = acc / fmaxf((float)(o1 - o0), 1.0f);
  // packed 2B store per lane (coalesced 128B row)
  agg[(size_t)node * H + lane] = (ushort_t)f2bf_bits(mean);
}

// ---------------- dense: thread-per-node, fp32 scalar-load weights -----------

// y = l2norm(agg@W1 + b1 + x@W2); if FUSE_LN: y = LN(relu(y)). bf16 in/out.
template<bool FUSE_LN>
__global__ __launch_bounds__(256)
void sage_partial(const ushort_t* __restrict__ agg, const ushort_t* __restrict__ xdst,
                  const float* __restrict__ W1, const float* __restrict__ b1,
                  const float* __restrict__ W2,
                  const float* __restrict__ g, const float* __restrict__ bb,
                  ushort_t* __restrict__ out, int N) {
  const int n = blockIdx.x * 256 + threadIdx.x;
  if (n >= N) return;
  float acc[H];
  #pragma unroll
  for (int j = 0; j < H; ++j) acc[j] = b1[j];
  const uint4* ar = (const uint4*)(agg + (size_t)n * H);
  const uint4* xr = (const uint4*)(xdst + (size_t)n * H);
  uint4 an = ar[0], xn = xr[0];
  for (int kb = 0; kb < 8; ++kb) {
    uint4 av = an, xv = xn;
    if (kb < 7) { an = ar[kb + 1]; xn = xr[kb + 1]; }
    float aa[8], xa[8];
    unpack8(av, aa);
    unpack8(xv, xa);
    #pragma unroll
    for (int dk = 0; dk < 8; ++dk) {
      const float4* w1r = (const float4*)(W1 + (size_t)(kb * 8 + dk) * H);
      const float4* w2r = (const float4*)(W2 + (size_t)(kb * 8 + dk) * H);
      #pragma unroll
      for (int jc = 0; jc < H / 4; ++jc) {
        float4 w1 = w1r[jc], w2 = w2r[jc];
        acc[jc * 4 + 0] = fmaf(aa[dk], w1.x, fmaf(xa[dk], w2.x, acc[jc * 4 + 0]));
        acc[jc * 4 + 1] = fmaf(aa[dk], w1.y, fmaf(xa[dk], w2.y, acc[jc * 4 + 1]));
        acc[jc * 4 + 2] = fmaf(aa[dk], w1.z, fmaf(xa[dk], w2.z, acc[jc * 4 + 2]));
        acc[jc * 4 + 3] = fmaf(aa[dk], w1.w, fmaf(xa[dk], w2.w, acc[jc * 4 + 3]));
      }
    }
  }
  float n2 = 0.0f;
  #pragma unroll
  for (int j = 0; j < H; ++j) n2 = fmaf(acc[j], acc[j], n2);
  const float r = 1.0f / fmaxf(sqrtf(n2), 1e-12f);
  if (FUSE_LN) {
    float m = 0.0f;
    #pragma unroll
    for (int j = 0; j < H; ++j) { acc[j] = fmaxf(acc[j] * r, 0.0f); m += acc[j]; }
    m *= (1.0f / H);
    float var = 0.0f;
    #pragma unroll
    for (int j = 0; j < H; ++j) { float d = acc[j] - m; var = fmaf(d, d, var); }
    const float s = rsqrtf(var * (1.0f / H) + 1e-5f);
    #pragma unroll
    for (int j = 0; j < H; ++j) acc[j] = (acc[j] - m) * s * g[j] + bb[j];
  } else {
    #pragma unroll
    for (int j = 0; j < H; ++j) acc[j] *= r;
  }
  uint4* orow = (uint4*)(out + (size_t)n * H);
  #pragma unroll
  for (int kb = 0; kb < 8; ++kb) {
    uint4 q;
    q.x = pack2(acc[kb * 8 + 0], acc[kb * 8 + 1]);
    q.y = pack2(acc[kb * 8 + 2], acc[kb * 8 + 3]);
    q.z = pack2(acc[kb * 8 + 4], acc[kb * 8 + 5]);
    q.w = pack2(acc[kb * 8 + 6], acc[kb * 8 + 7]);
    orow[kb] = q;
  }
}

// hs_new = LN(relu(0.5*(o2+o3)))
__global__ __launch_bounds__(256)
void combine_kernel(const ushort_t* __restrict__ o2, const ushort_t* __restrict__ o3,
                    const float* __restrict__ g, const float* __restrict__ bb,
                    ushort_t* __restrict__ out, int N) {
  const int n = blockIdx.x * 256 + threadIdx.x;
  if (n >= N) return;
  const uint4* r2 = (const uint4*)(o2 + (size_t)n * H);
  const uint4* r3 = (const uint4*)(o3 + (size_t)n * H);
  float y[H];
  float m = 0.0f;
  #pragma unroll
  for (int kb = 0; kb < 8; ++kb) {
    float a[8], b[8];
    unpack8(r2[kb], a);
    unpack8(r3[kb], b);
    #pragma unroll
    for (int i = 0; i < 8; ++i) {
      float v = fmaxf(0.5f * (a[i] + b[i]), 0.0f);
      y[kb * 8 + i] = v;
      m += v;
    }
  }
  m *= (1.0f / H);
  float var = 0.0f;
  #pragma unroll
  for (int j = 0; j < H; ++j) { float d = y[j] - m; var = fmaf(d, d, var); }
  const float s = rsqrtf(var * (1.0f / H) + 1e-5f);
  uint4* orow = (uint4*)(out + (size_t)n * H);
  #pragma unroll
  for (int kb = 0; kb < 8; ++kb) {
    float o[8];
    #pragma unroll
    for (int i = 0; i < 8; ++i)
      o[i] = (y[kb * 8 + i] - m) * s * g[kb * 8 + i] + bb[kb * 8 + i];
    uint4 q;
    q.x = pack2(o[0], o[1]); q.y = pack2(o[2], o[3]);
    q.z = pack2(o[4], o[5]); q.w = pack2(o[6], o[7]);
    orow[kb] = q;
  }
}

// y = relu(x @ W + b), fp32 x in, bf16 out
template<int K>
__global__ __launch_bounds__(256)
void proj_dense(const float* __restrict__ x, const float* __restrict__ W,
                const float* __restrict__ b, ushort_t* __restrict__ y, int N) {
  const int n = blockIdx.x * 256 + threadIdx.x;
  if (n >= N) return;
  float acc[H];
  #pragma unroll
  for (int j = 0; j < H; ++j) acc[j] = b[j];
  const float4* xr = (const float4*)(x + (size_t)n * K);
  float4 xn = xr[0];
  for (int kb = 0; kb < K / 4; ++kb) {
    float4 xv = xn;
    if (kb + 1 < K / 4) xn = xr[kb + 1];
    const float xa[4] = {xv.x, xv.y, xv.z, xv.w};
    #pragma unroll
    for (int dk = 0; dk < 4; ++dk) {
      const float4* wr = (const float4*)(W + (size_t)(kb * 4 + dk) * H);
      #pragma unroll
      for (int jc = 0; jc < H / 4; ++jc) {
        float4 w = wr[jc];
        acc[jc * 4 + 0] = fmaf(xa[dk], w.x, acc[jc * 4 + 0]);
        acc[jc * 4 + 1] = fmaf(xa[dk], w.y, acc[jc * 4 + 1]);
        acc[jc * 4 + 2] = fmaf(xa[dk], w.z, acc[jc * 4 + 2]);
        acc[jc * 4 + 3] = fmaf(xa[dk], w.w, acc[jc * 4 + 3]);
      }
    }
  }
  uint4* yr = (uint4*)(y + (size_t)n * H);
  #pragma unroll
  for (int kb = 0; kb < 8; ++kb) {
    uint4 q;
    q.x = pack2(fmaxf(acc[kb * 8 + 0], 0.0f), fmaxf(acc[kb * 8 + 1], 0.0f));
    q.y = pack2(fmaxf(acc[kb * 8 + 2], 0.0f), fmaxf(acc[kb * 8 + 3], 0.0f));
    q.z = pack2(fmaxf(acc[kb * 8 + 4], 0.0f), fmaxf(acc[kb * 8 + 5], 0.0f));
    q.w = pack2(fmaxf(acc[kb * 8 + 6], 0.0f), fmaxf(acc[kb * 8 + 7], 0.0f));
    yr[kb] = q;
  }
}

__global__ __launch_bounds__(256)
void reg_kernel(const ushort_t* __restrict__ hs, const float* __restrict__ Wreg,
                const float* __restrict__ breg, float* __restrict__ out, int N) {
  const int lane = threadIdx.x & 63;
  const int node = blockIdx.x * 4 + (threadIdx.x >> 6);
  if (node >= N) return;
  float t = bf2f(hs[(size_t)node * H + lane]) * Wreg[lane];
  t = wave_sum(t);
  if (lane == 0) out[node] = t + breg[0];
}

// -----------------------------------------------------------------------------

static inline void build_csr(const int* src, const int* dst, int N, int E,
                             int* hist_cur, int* off, int* csr, int* parts,
                             hipStream_t stream) {
  const int nb = (N + SCAN_CHUNK - 1) / SCAN_CHUNK;
  const int eb = (E + 255) / 256;
  hipMemsetAsync(hist_cur, 0, (size_t)N * sizeof(int), stream);
  hist_kernel<<<eb, 256, 0, stream>>>(dst, E, hist_cur);
  scan_block_totals<<<nb, 256, 0, stream>>>(hist_cur, N, parts);
  scan_partials<<<1, 64, 0, stream>>>(parts, nb);
  scan_final<<<nb, 256, 0, stream>>>(hist_cur, N, parts, off, hist_cur, E);
  reorder_kernel<<<eb, 256, 0, stream>>>(src, dst, E, hist_cur, csr);
}

extern "C" void kernel_launch(void* const* d_in, const int* in_sizes, int n_in,
                              void* d_out, int out_size, void* d_ws, size_t ws_size,
                              hipStream_t stream) {
  const float* x_stay  = (const float*)d_in[0];
  const float* x_pat   = (const float*)d_in[1];
  const float* Wp_stay = (const float*)d_in[2];
  const float* bp_stay = (const float*)d_in[3];
  const float* Wp_pat  = (const float*)d_in[4];
  const float* bp_pat  = (const float*)d_in[5];
  const float* Wl      = (const float*)d_in[6];
  const float* bl      = (const float*)d_in[7];
  const float* Wr      = (const float*)d_in[8];
  const float* ln_g    = (const float*)d_in[9];
  const float* ln_b    = (const float*)d_in[10];
  const float* Wreg    = (const float*)d_in[11];
  const float* breg    = (const float*)d_in[12];
  const int* e1s = (const int*)d_in[13];
  const int* e1d = (const int*)d_in[14];
  const int* e2s = (const int*)d_in[15];
  const int* e2d = (const int*)d_in[16];
  const int* e3s = (const int*)d_in[17];
  const int* e3d = (const int*)d_in[18];
  float* out = (float*)d_out;

  const size_t S = (size_t)N_STAY * H;
  const size_t P = (size_t)N_PAT * H;

  // bf16 feature buffers
  ushort_t* hs   = (ushort_t*)d_ws;
  ushort_t* hp   = hs + S;
  ushort_t* agg1 = hp + P;      // patient-sized
  ushort_t* agg2 = agg1 + P;    // stay-sized
  ushort_t* agg3 = agg2 + S;    // stay-sized
  // int region
  int* ib    = (int*)(agg3 + S);
  int* off1  = ib;                       // N_PAT+1
  int* off2  = off1 + (N_PAT + 1);       // N_STAY+1
  int* off3  = off2 + (N_STAY + 1);      // N_STAY+1
  int* hist1 = off3 + (N_STAY + 1);      // N_PAT   (doubles as cursor)
  int* hist2 = hist1 + N_PAT;            // N_STAY
  int* hist3 = hist2 + N_STAY;           // N_STAY
  int* csr1  = hist3 + N_STAY;           // E
  int* csr2  = csr1 + N_EDGE;            // E
  int* csr3  = csr2 + N_EDGE;            // E
  int* parts = csr3 + N_EDGE;            // 3*64

  // CSR builds (edges identical across layers -> build once)
  build_csr(e1s, e1d, N_PAT,  N_EDGE, hist1, off1, csr1, parts + 0,   stream);
  build_csr(e2s, e2d, N_STAY, N_EDGE, hist2, off2, csr2, parts + 64,  stream);
  build_csr(e3s, e3d, N_STAY, N_EDGE, hist3, off3, csr3, parts + 128, stream);

  // input projections
  proj_dense<128><<<(N_STAY + 255) / 256, 256, 0, stream>>>(x_stay, Wp_stay, bp_stay, hs, N_STAY);
  proj_dense<64><<<(N_PAT + 255) / 256, 256, 0, stream>>>(x_pat, Wp_pat, bp_pat, hp, N_PAT);

  const int AGG_S = (N_STAY * 64 + 255) / 256;  // wave per node
  const int AGG_P = (N_PAT * 64 + 255) / 256;
  const int TB_S = (N_STAY + 255) / 256;        // thread per node
  const int TB_P = (N_PAT + 255) / 256;

  for (int l = 0; l < 2; ++l) {
    const float* Wl0 = Wl + (size_t)(l * 3 + 0) * H * H;
    const float* Wl1 = Wl + (size_t)(l * 3 + 1) * H * H;
    const float* Wl2 = Wl + (size_t)(l * 3 + 2) * H * H;
    const float* Wr0 = Wr + (size_t)(l * 3 + 0) * H * H;
    const float* Wr1 = Wr + (size_t)(l * 3 + 1) * H * H;
    const float* Wr2 = Wr + (size_t)(l * 3 + 2) * H * H;
    const float* bl0 = bl + (size_t)(l * 3 + 0) * H;
    const float* bl1 = bl + (size_t)(l * 3 + 1) * H;
    const float* bl2 = bl + (size_t)(l * 3 + 2) * H;
    const float* g  = ln_g + (size_t)l * H;
    const float* bb = ln_b + (size_t)l * H;

    // gather-mean aggregations (must precede overwrites of hs/hp)
    agg_kernel<<<AGG_P, 256, 0, stream>>>(hs, off1, csr1, agg1, N_PAT);
    agg_kernel<<<AGG_S, 256, 0, stream>>>(hp, off2, csr2, agg2, N_STAY);
    agg_kernel<<<AGG_S, 256, 0, stream>>>(hs, off3, csr3, agg3, N_STAY);

    // patients: full fused (l2norm -> relu -> LN), in-place over hp
    sage_partial<true><<<TB_P, 256, 0, stream>>>(agg1, hp, Wl0, bl0, Wr0, g, bb, hp, N_PAT);
    // stays: two partials (l2norm only), in-place over agg buffers
    sage_partial<false><<<TB_S, 256, 0, stream>>>(agg2, hs, Wl1, bl1, Wr1, g, bb, agg2, N_STAY);
    sage_partial<false><<<TB_S, 256, 0, stream>>>(agg3, hs, Wl2, bl2, Wr2, g, bb, agg3, N_STAY);
    // combine + relu + LN -> hs
    combine_kernel<<<TB_S, 256, 0, stream>>>(agg2, agg3, g, bb, hs, N_STAY);
  }

  reg_kernel<<<(N_STAY + 3) / 4, 256, 0, stream>>>(hs, Wreg, breg, out, N_STAY);
}

// Round 4
// 1365.198 us; speedup vs baseline: 3.0006x; 1.4423x over previous
//
#include <hip/hip_runtime.h>

#define H 64
#define N_STAY 200000
#define N_PAT  100000
#define N_EDGE 1000000
#define SCAN_CHUNK 4096  // 256 threads * 16 elems

typedef unsigned short ushort_t;
typedef __attribute__((ext_vector_type(8))) short bf16x8;
typedef __attribute__((ext_vector_type(4))) float f32x4;

__device__ __forceinline__ float wave_sum(float v) {
  #pragma unroll
  for (int off = 32; off > 0; off >>= 1) v += __shfl_xor(v, off);
  return v;
}

__device__ __forceinline__ float bf2f(ushort_t u) {
  union { unsigned int i; float f; } c;
  c.i = ((unsigned int)u) << 16;
  return c.f;
}
__device__ __forceinline__ unsigned int f2bf_bits(float f) {
  union { float v; unsigned int i; } c; c.v = f;
  unsigned int r = c.i + 0x7fffu + ((c.i >> 16) & 1u);  // RNE
  return r >> 16;
}
__device__ __forceinline__ bf16x8 ld_frag(const ushort_t* p) {
  union { uint4 u; bf16x8 v; } c;
  c.u = *(const uint4*)p;
  return c.v;
}

// ---------------- CSR build --------------------------------------------------

__global__ __launch_bounds__(256)
void hist_kernel(const int* __restrict__ dst, int E, int* __restrict__ hist) {
  int e = blockIdx.x * 256 + threadIdx.x;
  if (e < E) atomicAdd(&hist[dst[e]], 1);
}

__global__ __launch_bounds__(256)
void scan_block_totals(const int* __restrict__ in, int n, int* __restrict__ partials) {
  int base = blockIdx.x * SCAN_CHUNK + threadIdx.x * 16;
  int s = 0;
  #pragma unroll
  for (int i = 0; i < 16; ++i) { int idx = base + i; if (idx < n) s += in[idx]; }
  #pragma unroll
  for (int off = 32; off > 0; off >>= 1) s += __shfl_xor(s, off);
  __shared__ int wsum[4];
  if ((threadIdx.x & 63) == 0) wsum[threadIdx.x >> 6] = s;
  __syncthreads();
  if (threadIdx.x == 0) partials[blockIdx.x] = wsum[0] + wsum[1] + wsum[2] + wsum[3];
}

__global__ __launch_bounds__(64)
void scan_partials(int* __restrict__ partials, int np) {
  int lane = threadIdx.x;
  int orig = (lane < np) ? partials[lane] : 0;
  int v = orig;
  #pragma unroll
  for (int off = 1; off < 64; off <<= 1) {
    int t = __shfl_up(v, off);
    if (lane >= off) v += t;
  }
  if (lane < np) partials[lane] = v - orig;  // exclusive
}

__global__ __launch_bounds__(256)
void scan_final(const int* __restrict__ in, int n, const int* __restrict__ partials,
                int* __restrict__ off, int* __restrict__ cur, int total) {
  int b = blockIdx.x, tid = threadIdx.x;
  int base = b * SCAN_CHUNK + tid * 16;
  int vals[16]; int s = 0;
  #pragma unroll
  for (int i = 0; i < 16; ++i) {
    int idx = base + i;
    vals[i] = (idx < n) ? in[idx] : 0;
    s += vals[i];
  }
  int lane = tid & 63, w = tid >> 6;
  int incl = s;
  #pragma unroll
  for (int o = 1; o < 64; o <<= 1) {
    int t = __shfl_up(incl, o);
    if (lane >= o) incl += t;
  }
  __shared__ int wtot[4];
  if (lane == 63) wtot[w] = incl;
  __syncthreads();
  int wbase = 0;
  for (int i = 0; i < w; ++i) wbase += wtot[i];
  int run = partials[b] + wbase + incl - s;
  #pragma unroll
  for (int i = 0; i < 16; ++i) {
    int idx = base + i;
    if (idx < n) { off[idx] = run; cur[idx] = run; run += vals[i]; }
  }
  if (b == 0 && tid == 0) off[n] = total;
}

__global__ __launch_bounds__(256)
void reorder_kernel(const int* __restrict__ src, const int* __restrict__ dst, int E,
                    int* __restrict__ cur, int* __restrict__ csr) {
  int e = blockIdx.x * 256 + threadIdx.x;
  if (e >= E) return;
  int d = dst[e];
  int pos = atomicAdd(&cur[d], 1);
  csr[pos] = src[e];
}

// ---------------- weight preconversion to MFMA B-fragments (hi+lo bf16) -----
// B-frag layout (16x16x32): lane holds B[k = (lane>>4)*8 + j][n = ntile*16 + (lane&15)]
// storage: mat*2*PLANE + plane*PLANE + (fid*64+lane)*8, fid = ntile*(K/32)+kstep

template<int K>
__global__ __launch_bounds__(256)
void precvt_kernel(const float* __restrict__ src, ushort_t* __restrict__ dst, int nmat) {
  const int KS = K / 32;
  const int FU = KS * 4;
  const int PLANE = FU * 64 * 8;
  int fu = blockIdx.x * 4 + (threadIdx.x >> 6);
  int lane = threadIdx.x & 63;
  int mi = fu / FU;
  if (mi >= nmat) return;
  int fid = fu % FU;
  int ntile = fid / KS;
  int kstep = fid % KS;
  int q = lane >> 4, n = ntile * 16 + (lane & 15);
  const float* W = src + (size_t)mi * K * H;
  union { ushort_t s[8]; uint4 u; } hi, lo;
  #pragma unroll
  for (int j = 0; j < 8; ++j) {
    float v = W[(size_t)(kstep * 32 + q * 8 + j) * H + n];
    unsigned hb = f2bf_bits(v);
    hi.s[j] = (ushort_t)hb;
    lo.s[j] = (ushort_t)f2bf_bits(v - bf2f((ushort_t)hb));
  }
  ushort_t* base = dst + (size_t)mi * 2 * PLANE + ((size_t)fid * 64 + lane) * 8;
  *(uint4*)base = hi.u;
  *(uint4*)(base + PLANE) = lo.u;
}

// ---------------- aggregation: wave per dst node, lane = feature -------------

__global__ __launch_bounds__(256)
void agg_kernel(const ushort_t* __restrict__ x, const int* __restrict__ off,
                const int* __restrict__ csr, ushort_t* __restrict__ agg, int N) {
  const int node = (int)((blockIdx.x * 256 + threadIdx.x) >> 6);
  const int lane = threadIdx.x & 63;
  if (node >= N) return;
  const int o0 = off[node], o1 = off[node + 1];
  float acc = 0.0f;
  for (int i = o0; i < o1; ++i) {
    int s = csr[i];
    acc += bf2f(x[(size_t)s * H + lane]);
  }
  float mean = acc / fmaxf((float)(o1 - o0), 1.0f);
  agg[(size_t)node * H + lane] = (ushort_t)f2bf_bits(mean);
}

// ---------------- MFMA dense kernels ----------------------------------------
// wave handles 16 rows. A-frag: lane holds row (lane&15), k = kstep*32+(lane>>4)*8..+8
// C/D: col = lane&15 (+16*ntile), row = (lane>>4)*4 + reg

#define MFMA16(a, b, c) __builtin_amdgcn_mfma_f32_16x16x32_bf16((a), (b), (c), 0, 0, 0)

// proj: y = relu(x @ W + b), fp32 x (split hi/lo), bf16 out
template<int K>
__global__ __launch_bounds__(256)
void proj_mfma(const float* __restrict__ x, const ushort_t* __restrict__ fw,
               const float* __restrict__ b, ushort_t* __restrict__ y, int N) {
  const int KS = K / 32;
  const int PLANE = KS * 4 * 64 * 8;
  const int wid = threadIdx.x >> 6, lane = threadIdx.x & 63;
  const int r0 = blockIdx.x * 64 + wid * 16;
  if (r0 >= N) return;
  const int m = lane & 15, q = lane >> 4;
  f32x4 c[4] = {{0,0,0,0},{0,0,0,0},{0,0,0,0},{0,0,0,0}};
  for (int ks = 0; ks < KS; ++ks) {
    const float* xp = x + (size_t)(r0 + m) * K + ks * 32 + q * 8;
    float4 v0 = *(const float4*)xp;
    float4 v1 = *(const float4*)(xp + 4);
    float vv[8] = {v0.x, v0.y, v0.z, v0.w, v1.x, v1.y, v1.z, v1.w};
    union { ushort_t s[8]; bf16x8 v; } ah, al;
    #pragma unroll
    for (int j = 0; j < 8; ++j) {
      unsigned hb = f2bf_bits(vv[j]);
      ah.s[j] = (ushort_t)hb;
      al.s[j] = (ushort_t)f2bf_bits(vv[j] - bf2f((ushort_t)hb));
    }
    #pragma unroll
    for (int nt = 0; nt < 4; ++nt) {
      const ushort_t* fb = fw + ((size_t)(nt * KS + ks) * 64 + lane) * 8;
      bf16x8 bh = ld_frag(fb);
      bf16x8 blo = ld_frag(fb + PLANE);
      c[nt] = MFMA16(ah.v, bh, c[nt]);
      c[nt] = MFMA16(ah.v, blo, c[nt]);
      c[nt] = MFMA16(al.v, bh, c[nt]);
    }
  }
  #pragma unroll
  for (int nt = 0; nt < 4; ++nt) {
    float bias = b[nt * 16 + m];
    #pragma unroll
    for (int r = 0; r < 4; ++r) {
      float o = fmaxf(c[nt][r] + bias, 0.0f);
      y[(size_t)(r0 + q * 4 + r) * H + nt * 16 + m] = (ushort_t)f2bf_bits(o);
    }
  }
}

// patients: out = LN(relu(l2norm(agg@W1 + b1 + x@W2))). in-place over x ok.
__global__ __launch_bounds__(256)
void sage_pat_mfma(const ushort_t* __restrict__ agg, const ushort_t* __restrict__ x,
                   const ushort_t* __restrict__ fW1, const ushort_t* __restrict__ fW2,
                   const float* __restrict__ b1,
                   const float* __restrict__ g, const float* __restrict__ bb,
                   ushort_t* __restrict__ out, int N) {
  const int PLANE = 4096;
  const int wid = threadIdx.x >> 6, lane = threadIdx.x & 63;
  const int r0 = blockIdx.x * 64 + wid * 16;
  if (r0 >= N) return;
  const int m = lane & 15, q = lane >> 4;
  const ushort_t* ap = agg + (size_t)(r0 + m) * H + q * 8;
  const ushort_t* xp = x + (size_t)(r0 + m) * H + q * 8;
  bf16x8 A[2], X[2];
  A[0] = ld_frag(ap); A[1] = ld_frag(ap + 32);
  X[0] = ld_frag(xp); X[1] = ld_frag(xp + 32);
  f32x4 c[4] = {{0,0,0,0},{0,0,0,0},{0,0,0,0},{0,0,0,0}};
  #pragma unroll
  for (int nt = 0; nt < 4; ++nt) {
    #pragma unroll
    for (int ks = 0; ks < 2; ++ks) {
      const size_t fo = ((size_t)(nt * 2 + ks) * 64 + lane) * 8;
      bf16x8 bh = ld_frag(fW1 + fo), blo = ld_frag(fW1 + PLANE + fo);
      c[nt] = MFMA16(A[ks], bh, c[nt]);
      c[nt] = MFMA16(A[ks], blo, c[nt]);
      bh = ld_frag(fW2 + fo); blo = ld_frag(fW2 + PLANE + fo);
      c[nt] = MFMA16(X[ks], bh, c[nt]);
      c[nt] = MFMA16(X[ks], blo, c[nt]);
    }
  }
  float n2s[4] = {0, 0, 0, 0};
  #pragma unroll
  for (int nt = 0; nt < 4; ++nt) {
    float bias = b1[nt * 16 + m];
    #pragma unroll
    for (int r = 0; r < 4; ++r) {
      c[nt][r] += bias;
      n2s[r] = fmaf(c[nt][r], c[nt][r], n2s[r]);
    }
  }
  #pragma unroll
  for (int off = 1; off < 16; off <<= 1)
    #pragma unroll
    for (int r = 0; r < 4; ++r) n2s[r] += __shfl_xor(n2s[r], off);
  float rv[4];
  #pragma unroll
  for (int r = 0; r < 4; ++r) rv[r] = 1.0f / fmaxf(sqrtf(n2s[r]), 1e-12f);
  float y[4][4];
  float s1[4] = {0,0,0,0}, s2[4] = {0,0,0,0};
  #pragma unroll
  for (int nt = 0; nt < 4; ++nt)
    #pragma unroll
    for (int r = 0; r < 4; ++r) {
      float v = fmaxf(c[nt][r] * rv[r], 0.0f);
      y[nt][r] = v;
      s1[r] += v;
      s2[r] = fmaf(v, v, s2[r]);
    }
  #pragma unroll
  for (int off = 1; off < 16; off <<= 1)
    #pragma unroll
    for (int r = 0; r < 4; ++r) {
      s1[r] += __shfl_xor(s1[r], off);
      s2[r] += __shfl_xor(s2[r], off);
    }
  float mean[4], sig[4];
  #pragma unroll
  for (int r = 0; r < 4; ++r) {
    mean[r] = s1[r] * (1.0f / H);
    float var = s2[r] * (1.0f / H) - mean[r] * mean[r];
    sig[r] = rsqrtf(var + 1e-5f);
  }
  #pragma unroll
  for (int nt = 0; nt < 4; ++nt) {
    float gv = g[nt * 16 + m], bv = bb[nt * 16 + m];
    #pragma unroll
    for (int r = 0; r < 4; ++r) {
      float o = (y[nt][r] - mean[r]) * sig[r] * gv + bv;
      out[(size_t)(r0 + q * 4 + r) * H + nt * 16 + m] = (ushort_t)f2bf_bits(o);
    }
  }
}

// stays fused: y2=l2norm(agg2@Wl2+bl2+x@Wr2); y3=l2norm(agg3@Wl3+bl3+x@Wr3)
// out = LN(relu(0.5*(y2+y3))). in-place over x ok.
__global__ __launch_bounds__(256)
void sage_stay_mfma(const ushort_t* __restrict__ agg2, const ushort_t* __restrict__ agg3,
                    const ushort_t* __restrict__ x,
                    const ushort_t* __restrict__ fWl2, const ushort_t* __restrict__ fWr2,
                    const ushort_t* __restrict__ fWl3, const ushort_t* __restrict__ fWr3,
                    const float* __restrict__ bl2, const float* __restrict__ bl3,
                    const float* __restrict__ g, const float* __restrict__ bb,
                    ushort_t* __restrict__ out, int N) {
  const int PLANE = 4096;
  const int wid = threadIdx.x >> 6, lane = threadIdx.x & 63;
  const int r0 = blockIdx.x * 64 + wid * 16;
  if (r0 >= N) return;
  const int m = lane & 15, q = lane >> 4;
  const ushort_t* a2p = agg2 + (size_t)(r0 + m) * H + q * 8;
  const ushort_t* a3p = agg3 + (size_t)(r0 + m) * H + q * 8;
  const ushort_t* xp  = x    + (size_t)(r0 + m) * H + q * 8;
  bf16x8 A2[2], A3[2], X[2];
  A2[0] = ld_frag(a2p); A2[1] = ld_frag(a2p + 32);
  A3[0] = ld_frag(a3p); A3[1] = ld_frag(a3p + 32);
  X[0]  = ld_frag(xp);  X[1]  = ld_frag(xp + 32);
  f32x4 c2[4] = {{0,0,0,0},{0,0,0,0},{0,0,0,0},{0,0,0,0}};
  f32x4 c3[4] = {{0,0,0,0},{0,0,0,0},{0,0,0,0},{0,0,0,0}};
  #pragma unroll
  for (int nt = 0; nt < 4; ++nt) {
    #pragma unroll
    for (int ks = 0; ks < 2; ++ks) {
      const size_t fo = ((size_t)(nt * 2 + ks) * 64 + lane) * 8;
      bf16x8 bh = ld_frag(fWl2 + fo), blo = ld_frag(fWl2 + PLANE + fo);
      c2[nt] = MFMA16(A2[ks], bh, c2[nt]);
      c2[nt] = MFMA16(A2[ks], blo, c2[nt]);
      bh = ld_frag(fWr2 + fo); blo = ld_frag(fWr2 + PLANE + fo);
      c2[nt] = MFMA16(X[ks], bh, c2[nt]);
      c2[nt] = MFMA16(X[ks], blo, c2[nt]);
      bh = ld_frag(fWl3 + fo); blo = ld_frag(fWl3 + PLANE + fo);
      c3[nt] = MFMA16(A3[ks], bh, c3[nt]);
      c3[nt] = MFMA16(A3[ks], blo, c3[nt]);
      bh = ld_frag(fWr3 + fo); blo = ld_frag(fWr3 + PLANE + fo);
      c3[nt] = MFMA16(X[ks], bh, c3[nt]);
      c3[nt] = MFMA16(X[ks], blo, c3[nt]);
    }
  }
  float n2s[4] = {0,0,0,0}, n3s[4] = {0,0,0,0};
  #pragma unroll
  for (int nt = 0; nt < 4; ++nt) {
    float b2 = bl2[nt * 16 + m], b3 = bl3[nt * 16 + m];
    #pragma unroll
    for (int r = 0; r < 4; ++r) {
      c2[nt][r] += b2;
      c3[nt][r] += b3;
      n2s[r] = fmaf(c2[nt][r], c2[nt][r], n2s[r]);
      n3s[r] = fmaf(c3[nt][r], c3[nt][r], n3s[r]);
    }
  }
  #pragma unroll
  for (int off = 1; off < 16; off <<= 1)
    #pragma unroll
    for (int r = 0; r < 4; ++r) {
      n2s[r] += __shfl_xor(n2s[r], off);
      n3s[r] += __shfl_xor(n3s[r], off);
    }
  float r2v[4], r3v[4];
  #pragma unroll
  for (int r = 0; r < 4; ++r) {
    r2v[r] = 0.5f / fmaxf(sqrtf(n2s[r]), 1e-12f);  // fold 0.5 avg
    r3v[r] = 0.5f / fmaxf(sqrtf(n3s[r]), 1e-12f);
  }
  float y[4][4];
  float s1[4] = {0,0,0,0}, s2[4] = {0,0,0,0};
  #pragma unroll
  for (int nt = 0; nt < 4; ++nt)
    #pragma unroll
    for (int r = 0; r < 4; ++r) {
      float v = fmaxf(fmaf(c2[nt][r], r2v[r], c3[nt][r] * r3v[r]), 0.0f);
      y[nt][r] = v;
      s1[r] += v;
      s2[r] = fmaf(v, v, s2[r]);
    }
  #pragma unroll
  for (int off = 1; off < 16; off <<= 1)
    #pragma unroll
    for (int r = 0; r < 4; ++r) {
      s1[r] += __shfl_xor(s1[r], off);
      s2[r] += __shfl_xor(s2[r], off);
    }
  float mean[4], sig[4];
  #pragma unroll
  for (int r = 0; r < 4; ++r) {
    mean[r] = s1[r] * (1.0f / H);
    float var = s2[r] * (1.0f / H) - mean[r] * mean[r];
    sig[r] = rsqrtf(var + 1e-5f);
  }
  #pragma unroll
  for (int nt = 0; nt < 4; ++nt) {
    float gv = g[nt * 16 + m], bv = bb[nt * 16 + m];
    #pragma unroll
    for (int r = 0; r < 4; ++r) {
      float o = (y[nt][r] - mean[r]) * sig[r] * gv + bv;
      out[(size_t)(r0 + q * 4 + r) * H + nt * 16 + m] = (ushort_t)f2bf_bits(o);
    }
  }
}

__global__ __launch_bounds__(256)
void reg_kernel(const ushort_t* __restrict__ hs, const float* __restrict__ Wreg,
                const float* __restrict__ breg, float* __restrict__ out, int N) {
  const int lane = threadIdx.x & 63;
  const int node = blockIdx.x * 4 + (threadIdx.x >> 6);
  if (node >= N) return;
  float t = bf2f(hs[(size_t)node * H + lane]) * Wreg[lane];
  t = wave_sum(t);
  if (lane == 0) out[node] = t + breg[0];
}

// -----------------------------------------------------------------------------

static inline void build_csr(const int* src, const int* dst, int N, int E,
                             int* hist_cur, int* off, int* csr, int* parts,
                             hipStream_t stream) {
  const int nb = (N + SCAN_CHUNK - 1) / SCAN_CHUNK;
  const int eb = (E + 255) / 256;
  hipMemsetAsync(hist_cur, 0, (size_t)N * sizeof(int), stream);
  hist_kernel<<<eb, 256, 0, stream>>>(dst, E, hist_cur);
  scan_block_totals<<<nb, 256, 0, stream>>>(hist_cur, N, parts);
  scan_partials<<<1, 64, 0, stream>>>(parts, nb);
  scan_final<<<nb, 256, 0, stream>>>(hist_cur, N, parts, off, hist_cur, E);
  reorder_kernel<<<eb, 256, 0, stream>>>(src, dst, E, hist_cur, csr);
}

extern "C" void kernel_launch(void* const* d_in, const int* in_sizes, int n_in,
                              void* d_out, int out_size, void* d_ws, size_t ws_size,
                              hipStream_t stream) {
  const float* x_stay  = (const float*)d_in[0];
  const float* x_pat   = (const float*)d_in[1];
  const float* Wp_stay = (const float*)d_in[2];
  const float* bp_stay = (const float*)d_in[3];
  const float* Wp_pat  = (const float*)d_in[4];
  const float* bp_pat  = (const float*)d_in[5];
  const float* Wl      = (const float*)d_in[6];
  const float* bl      = (const float*)d_in[7];
  const float* Wr      = (const float*)d_in[8];
  const float* ln_g    = (const float*)d_in[9];
  const float* ln_b    = (const float*)d_in[10];
  const float* Wreg    = (const float*)d_in[11];
  const float* breg    = (const float*)d_in[12];
  const int* e1s = (const int*)d_in[13];
  const int* e1d = (const int*)d_in[14];
  const int* e2s = (const int*)d_in[15];
  const int* e2d = (const int*)d_in[16];
  const int* e3s = (const int*)d_in[17];
  const int* e3d = (const int*)d_in[18];
  float* out = (float*)d_out;

  const size_t S = (size_t)N_STAY * H;
  const size_t P = (size_t)N_PAT * H;

  // bf16 feature buffers
  ushort_t* hs   = (ushort_t*)d_ws;
  ushort_t* hp   = hs + S;
  ushort_t* agg1 = hp + P;      // patient-sized
  ushort_t* agg2 = agg1 + P;    // stay-sized
  ushort_t* agg3 = agg2 + S;    // stay-sized
  // preconverted weight fragments (hi+lo bf16 planes)
  ushort_t* fragW = agg3 + S;
  ushort_t* fWpS = fragW;                // K=128: 2*8192
  ushort_t* fWpP = fragW + 16384;        // K=64:  2*4096
  ushort_t* fWlB = fragW + 24576;        // 6 matrices * 8192
  ushort_t* fWrB = fragW + 24576 + 49152;
  // int region
  int* ib    = (int*)(fragW + 122880);
  int* off1  = ib;
  int* off2  = off1 + (N_PAT + 1);
  int* off3  = off2 + (N_STAY + 1);
  int* hist1 = off3 + (N_STAY + 1);
  int* hist2 = hist1 + N_PAT;
  int* hist3 = hist2 + N_STAY;
  int* csr1  = hist3 + N_STAY;
  int* csr2  = csr1 + N_EDGE;
  int* csr3  = csr2 + N_EDGE;
  int* parts = csr3 + N_EDGE;

  // weight preconversion (tiny, once per call)
  precvt_kernel<128><<<4, 256, 0, stream>>>(Wp_stay, fWpS, 1);
  precvt_kernel<64><<<2, 256, 0, stream>>>(Wp_pat, fWpP, 1);
  precvt_kernel<64><<<12, 256, 0, stream>>>(Wl, fWlB, 6);
  precvt_kernel<64><<<12, 256, 0, stream>>>(Wr, fWrB, 6);

  // CSR builds (edges identical across layers -> build once)
  build_csr(e1s, e1d, N_PAT,  N_EDGE, hist1, off1, csr1, parts + 0,   stream);
  build_csr(e2s, e2d, N_STAY, N_EDGE, hist2, off2, csr2, parts + 64,  stream);
  build_csr(e3s, e3d, N_STAY, N_EDGE, hist3, off3, csr3, parts + 128, stream);

  // input projections (MFMA, fp32 inputs hi/lo split)
  proj_mfma<128><<<(N_STAY + 63) / 64, 256, 0, stream>>>(x_stay, fWpS, bp_stay, hs, N_STAY);
  proj_mfma<64><<<(N_PAT + 63) / 64, 256, 0, stream>>>(x_pat, fWpP, bp_pat, hp, N_PAT);

  const int AGG_S = (N_STAY * 64 + 255) / 256;
  const int AGG_P = (N_PAT * 64 + 255) / 256;

  for (int l = 0; l < 2; ++l) {
    ushort_t* fWl0 = fWlB + (size_t)(l * 3 + 0) * 8192;
    ushort_t* fWl1 = fWlB + (size_t)(l * 3 + 1) * 8192;
    ushort_t* fWl2 = fWlB + (size_t)(l * 3 + 2) * 8192;
    ushort_t* fWr0 = fWrB + (size_t)(l * 3 + 0) * 8192;
    ushort_t* fWr1 = fWrB + (size_t)(l * 3 + 1) * 8192;
    ushort_t* fWr2 = fWrB + (size_t)(l * 3 + 2) * 8192;
    const float* bl0 = bl + (size_t)(l * 3 + 0) * H;
    const float* bl1 = bl + (size_t)(l * 3 + 1) * H;
    const float* bl2 = bl + (size_t)(l * 3 + 2) * H;
    const float* g  = ln_g + (size_t)l * H;
    const float* bb = ln_b + (size_t)l * H;

    // gather-mean aggregations (read hs/hp before they are overwritten)
    agg_kernel<<<AGG_P, 256, 0, stream>>>(hs, off1, csr1, agg1, N_PAT);
    agg_kernel<<<AGG_S, 256, 0, stream>>>(hp, off2, csr2, agg2, N_STAY);
    agg_kernel<<<AGG_S, 256, 0, stream>>>(hs, off3, csr3, agg3, N_STAY);

    // patients: fused sage + relu + LN, in-place over hp
    sage_pat_mfma<<<(N_PAT + 63) / 64, 256, 0, stream>>>(
        agg1, hp, fWl0, fWr0, bl0, g, bb, hp, N_PAT);
    // stays: both edge types fused + avg + relu + LN, in-place over hs
    sage_stay_mfma<<<(N_STAY + 63) / 64, 256, 0, stream>>>(
        agg2, agg3, hs, fWl1, fWr1, fWl2, fWr2, bl1, bl2, g, bb, hs, N_STAY);
  }

  reg_kernel<<<(N_STAY + 3) / 4, 256, 0, stream>>>(hs, Wreg, breg, out, N_STAY);
}

// Round 5
// 1093.894 us; speedup vs baseline: 3.7448x; 1.2480x over previous
//
#include <hip/hip_runtime.h>

#define H 64
#define N_STAY 200000
#define N_PAT  100000
#define N_EDGE 1000000
#define SCAN_CHUNK 4096  // 256 threads * 16 elems

typedef unsigned short ushort_t;
typedef __attribute__((ext_vector_type(8))) short bf16x8;
typedef __attribute__((ext_vector_type(4))) float f32x4;

__device__ __forceinline__ float wave_sum(float v) {
  #pragma unroll
  for (int off = 32; off > 0; off >>= 1) v += __shfl_xor(v, off);
  return v;
}

__device__ __forceinline__ float bf2f(ushort_t u) {
  union { unsigned int i; float f; } c;
  c.i = ((unsigned int)u) << 16;
  return c.f;
}
__device__ __forceinline__ unsigned int f2bf_bits(float f) {
  union { float v; unsigned int i; } c; c.v = f;
  unsigned int r = c.i + 0x7fffu + ((c.i >> 16) & 1u);  // RNE
  return r >> 16;
}
__device__ __forceinline__ unsigned int pack2(float lo, float hi) {
  return f2bf_bits(lo) | (f2bf_bits(hi) << 16);
}
__device__ __forceinline__ void unpack8(uint4 q, float* f) {
  union { unsigned int i; float v; } c;
  c.i = q.x << 16;          f[0] = c.v;
  c.i = q.x & 0xffff0000u;  f[1] = c.v;
  c.i = q.y << 16;          f[2] = c.v;
  c.i = q.y & 0xffff0000u;  f[3] = c.v;
  c.i = q.z << 16;          f[4] = c.v;
  c.i = q.z & 0xffff0000u;  f[5] = c.v;
  c.i = q.w << 16;          f[6] = c.v;
  c.i = q.w & 0xffff0000u;  f[7] = c.v;
}
__device__ __forceinline__ bf16x8 ld_frag(const ushort_t* p) {
  union { uint4 u; bf16x8 v; } c;
  c.u = *(const uint4*)p;
  return c.v;
}

// ---------------- CSR build --------------------------------------------------

// 3 edge lists in one dispatch: block range selects the list
__global__ __launch_bounds__(256)
void hist3_kernel(const int* __restrict__ d1, const int* __restrict__ d2,
                  const int* __restrict__ d3,
                  int* __restrict__ h1, int* __restrict__ h2, int* __restrict__ h3,
                  int eb) {
  int which = blockIdx.x / eb;
  int e = (blockIdx.x % eb) * 256 + threadIdx.x;
  if (e >= N_EDGE) return;
  if (which == 0)      atomicAdd(&h1[d1[e]], 1);
  else if (which == 1) atomicAdd(&h2[d2[e]], 1);
  else                 atomicAdd(&h3[d3[e]], 1);
}

__global__ __launch_bounds__(256)
void scan_block_totals(const int* __restrict__ in, int n, int* __restrict__ partials) {
  int base = blockIdx.x * SCAN_CHUNK + threadIdx.x * 16;
  int s = 0;
  #pragma unroll
  for (int i = 0; i < 16; ++i) { int idx = base + i; if (idx < n) s += in[idx]; }
  #pragma unroll
  for (int off = 32; off > 0; off >>= 1) s += __shfl_xor(s, off);
  __shared__ int wsum[4];
  if ((threadIdx.x & 63) == 0) wsum[threadIdx.x >> 6] = s;
  __syncthreads();
  if (threadIdx.x == 0) partials[blockIdx.x] = wsum[0] + wsum[1] + wsum[2] + wsum[3];
}

__global__ __launch_bounds__(64)
void scan_partials(int* __restrict__ partials, int np) {
  int lane = threadIdx.x;
  int orig = (lane < np) ? partials[lane] : 0;
  int v = orig;
  #pragma unroll
  for (int off = 1; off < 64; off <<= 1) {
    int t = __shfl_up(v, off);
    if (lane >= off) v += t;
  }
  if (lane < np) partials[lane] = v - orig;  // exclusive
}

__global__ __launch_bounds__(256)
void scan_final(const int* __restrict__ in, int n, const int* __restrict__ partials,
                int* __restrict__ off, int* __restrict__ cur, int total) {
  int b = blockIdx.x, tid = threadIdx.x;
  int base = b * SCAN_CHUNK + tid * 16;
  int vals[16]; int s = 0;
  #pragma unroll
  for (int i = 0; i < 16; ++i) {
    int idx = base + i;
    vals[i] = (idx < n) ? in[idx] : 0;
    s += vals[i];
  }
  int lane = tid & 63, w = tid >> 6;
  int incl = s;
  #pragma unroll
  for (int o = 1; o < 64; o <<= 1) {
    int t = __shfl_up(incl, o);
    if (lane >= o) incl += t;
  }
  __shared__ int wtot[4];
  if (lane == 63) wtot[w] = incl;
  __syncthreads();
  int wbase = 0;
  for (int i = 0; i < w; ++i) wbase += wtot[i];
  int run = partials[b] + wbase + incl - s;
  #pragma unroll
  for (int i = 0; i < 16; ++i) {
    int idx = base + i;
    if (idx < n) { off[idx] = run; cur[idx] = run; run += vals[i]; }
  }
  if (b == 0 && tid == 0) off[n] = total;
}

__global__ __launch_bounds__(256)
void reorder3_kernel(const int* __restrict__ s1, const int* __restrict__ d1,
                     const int* __restrict__ s2, const int* __restrict__ d2,
                     const int* __restrict__ s3, const int* __restrict__ d3,
                     int* __restrict__ c1, int* __restrict__ c2, int* __restrict__ c3,
                     int* __restrict__ r1, int* __restrict__ r2, int* __restrict__ r3,
                     int eb) {
  int which = blockIdx.x / eb;
  int e = (blockIdx.x % eb) * 256 + threadIdx.x;
  if (e >= N_EDGE) return;
  if (which == 0)      { int pos = atomicAdd(&c1[d1[e]], 1); r1[pos] = s1[e]; }
  else if (which == 1) { int pos = atomicAdd(&c2[d2[e]], 1); r2[pos] = s2[e]; }
  else                 { int pos = atomicAdd(&c3[d3[e]], 1); r3[pos] = s3[e]; }
}

// ---------------- weight preconversion to MFMA B-fragments (hi+lo bf16) -----

template<int K>
__global__ __launch_bounds__(256)
void precvt_kernel(const float* __restrict__ src, ushort_t* __restrict__ dst, int nmat) {
  const int KS = K / 32;
  const int FU = KS * 4;
  const int PLANE = FU * 64 * 8;
  int fu = blockIdx.x * 4 + (threadIdx.x >> 6);
  int lane = threadIdx.x & 63;
  int mi = fu / FU;
  if (mi >= nmat) return;
  int fid = fu % FU;
  int ntile = fid / KS;
  int kstep = fid % KS;
  int q = lane >> 4, n = ntile * 16 + (lane & 15);
  const float* W = src + (size_t)mi * K * H;
  union { ushort_t s[8]; uint4 u; } hi, lo;
  #pragma unroll
  for (int j = 0; j < 8; ++j) {
    float v = W[(size_t)(kstep * 32 + q * 8 + j) * H + n];
    unsigned hb = f2bf_bits(v);
    hi.s[j] = (ushort_t)hb;
    lo.s[j] = (ushort_t)f2bf_bits(v - bf2f((ushort_t)hb));
  }
  ushort_t* base = dst + (size_t)mi * 2 * PLANE + ((size_t)fid * 64 + lane) * 8;
  *(uint4*)base = hi.u;
  *(uint4*)(base + PLANE) = lo.u;
}

// ---------------- aggregation: wave per dst node, 8 edges x 8 lanes ----------
// lane = slot*8 + fg: slot picks edge within a batch of 8, fg picks 8 features.
// Each iteration gathers 8 full rows (1 KiB coalesced); slot-partials reduced
// by 3-step shfl_xor at the end.

__global__ __launch_bounds__(256)
void agg_kernel(const ushort_t* __restrict__ x, const int* __restrict__ off,
                const int* __restrict__ csr, ushort_t* __restrict__ agg, int N) {
  const int node = (int)((blockIdx.x * 256 + threadIdx.x) >> 6);
  const int lane = threadIdx.x & 63;
  if (node >= N) return;
  const int o0 = off[node], o1 = off[node + 1];
  const int slot = lane >> 3;
  const int fg = lane & 7;
  float acc[8] = {0, 0, 0, 0, 0, 0, 0, 0};
  for (int t = o0 + slot; t < o1; t += 8) {
    int s = csr[t];
    uint4 q = *(const uint4*)(x + (size_t)s * H + fg * 8);
    float f[8];
    unpack8(q, f);
    #pragma unroll
    for (int j = 0; j < 8; ++j) acc[j] += f[j];
  }
  #pragma unroll
  for (int o = 8; o < 64; o <<= 1)
    #pragma unroll
    for (int j = 0; j < 8; ++j) acc[j] += __shfl_xor(acc[j], o);
  if (slot == 0) {
    const float inv = 1.0f / fmaxf((float)(o1 - o0), 1.0f);
    uint4 q;
    q.x = pack2(acc[0] * inv, acc[1] * inv);
    q.y = pack2(acc[2] * inv, acc[3] * inv);
    q.z = pack2(acc[4] * inv, acc[5] * inv);
    q.w = pack2(acc[6] * inv, acc[7] * inv);
    *(uint4*)(agg + (size_t)node * H + fg * 8) = q;
  }
}

// ---------------- MFMA dense kernels ----------------------------------------

#define MFMA16(a, b, c) __builtin_amdgcn_mfma_f32_16x16x32_bf16((a), (b), (c), 0, 0, 0)

template<int K>
__global__ __launch_bounds__(256)
void proj_mfma(const float* __restrict__ x, const ushort_t* __restrict__ fw,
               const float* __restrict__ b, ushort_t* __restrict__ y, int N) {
  const int KS = K / 32;
  const int PLANE = KS * 4 * 64 * 8;
  const int wid = threadIdx.x >> 6, lane = threadIdx.x & 63;
  const int r0 = blockIdx.x * 64 + wid * 16;
  if (r0 >= N) return;
  const int m = lane & 15, q = lane >> 4;
  f32x4 c[4] = {{0,0,0,0},{0,0,0,0},{0,0,0,0},{0,0,0,0}};
  for (int ks = 0; ks < KS; ++ks) {
    const float* xp = x + (size_t)(r0 + m) * K + ks * 32 + q * 8;
    float4 v0 = *(const float4*)xp;
    float4 v1 = *(const float4*)(xp + 4);
    float vv[8] = {v0.x, v0.y, v0.z, v0.w, v1.x, v1.y, v1.z, v1.w};
    union { ushort_t s[8]; bf16x8 v; } ah, al;
    #pragma unroll
    for (int j = 0; j < 8; ++j) {
      unsigned hb = f2bf_bits(vv[j]);
      ah.s[j] = (ushort_t)hb;
      al.s[j] = (ushort_t)f2bf_bits(vv[j] - bf2f((ushort_t)hb));
    }
    #pragma unroll
    for (int nt = 0; nt < 4; ++nt) {
      const ushort_t* fb = fw + ((size_t)(nt * KS + ks) * 64 + lane) * 8;
      bf16x8 bh = ld_frag(fb);
      bf16x8 blo = ld_frag(fb + PLANE);
      c[nt] = MFMA16(ah.v, bh, c[nt]);
      c[nt] = MFMA16(ah.v, blo, c[nt]);
      c[nt] = MFMA16(al.v, bh, c[nt]);
    }
  }
  #pragma unroll
  for (int nt = 0; nt < 4; ++nt) {
    float bias = b[nt * 16 + m];
    #pragma unroll
    for (int r = 0; r < 4; ++r) {
      float o = fmaxf(c[nt][r] + bias, 0.0f);
      y[(size_t)(r0 + q * 4 + r) * H + nt * 16 + m] = (ushort_t)f2bf_bits(o);
    }
  }
}

__global__ __launch_bounds__(256)
void sage_pat_mfma(const ushort_t* __restrict__ agg, const ushort_t* __restrict__ x,
                   const ushort_t* __restrict__ fW1, const ushort_t* __restrict__ fW2,
                   const float* __restrict__ b1,
                   const float* __restrict__ g, const float* __restrict__ bb,
                   ushort_t* __restrict__ out, int N) {
  const int PLANE = 4096;
  const int wid = threadIdx.x >> 6, lane = threadIdx.x & 63;
  const int r0 = blockIdx.x * 64 + wid * 16;
  if (r0 >= N) return;
  const int m = lane & 15, q = lane >> 4;
  const ushort_t* ap = agg + (size_t)(r0 + m) * H + q * 8;
  const ushort_t* xp = x + (size_t)(r0 + m) * H + q * 8;
  bf16x8 A[2], X[2];
  A[0] = ld_frag(ap); A[1] = ld_frag(ap + 32);
  X[0] = ld_frag(xp); X[1] = ld_frag(xp + 32);
  f32x4 c[4] = {{0,0,0,0},{0,0,0,0},{0,0,0,0},{0,0,0,0}};
  #pragma unroll
  for (int nt = 0; nt < 4; ++nt) {
    #pragma unroll
    for (int ks = 0; ks < 2; ++ks) {
      const size_t fo = ((size_t)(nt * 2 + ks) * 64 + lane) * 8;
      bf16x8 bh = ld_frag(fW1 + fo), blo = ld_frag(fW1 + PLANE + fo);
      c[nt] = MFMA16(A[ks], bh, c[nt]);
      c[nt] = MFMA16(A[ks], blo, c[nt]);
      bh = ld_frag(fW2 + fo); blo = ld_frag(fW2 + PLANE + fo);
      c[nt] = MFMA16(X[ks], bh, c[nt]);
      c[nt] = MFMA16(X[ks], blo, c[nt]);
    }
  }
  float n2s[4] = {0, 0, 0, 0};
  #pragma unroll
  for (int nt = 0; nt < 4; ++nt) {
    float bias = b1[nt * 16 + m];
    #pragma unroll
    for (int r = 0; r < 4; ++r) {
      c[nt][r] += bias;
      n2s[r] = fmaf(c[nt][r], c[nt][r], n2s[r]);
    }
  }
  #pragma unroll
  for (int off = 1; off < 16; off <<= 1)
    #pragma unroll
    for (int r = 0; r < 4; ++r) n2s[r] += __shfl_xor(n2s[r], off);
  float rv[4];
  #pragma unroll
  for (int r = 0; r < 4; ++r) rv[r] = 1.0f / fmaxf(sqrtf(n2s[r]), 1e-12f);
  float y[4][4];
  float s1[4] = {0,0,0,0}, s2[4] = {0,0,0,0};
  #pragma unroll
  for (int nt = 0; nt < 4; ++nt)
    #pragma unroll
    for (int r = 0; r < 4; ++r) {
      float v = fmaxf(c[nt][r] * rv[r], 0.0f);
      y[nt][r] = v;
      s1[r] += v;
      s2[r] = fmaf(v, v, s2[r]);
    }
  #pragma unroll
  for (int off = 1; off < 16; off <<= 1)
    #pragma unroll
    for (int r = 0; r < 4; ++r) {
      s1[r] += __shfl_xor(s1[r], off);
      s2[r] += __shfl_xor(s2[r], off);
    }
  float mean[4], sig[4];
  #pragma unroll
  for (int r = 0; r < 4; ++r) {
    mean[r] = s1[r] * (1.0f / H);
    float var = s2[r] * (1.0f / H) - mean[r] * mean[r];
    sig[r] = rsqrtf(var + 1e-5f);
  }
  #pragma unroll
  for (int nt = 0; nt < 4; ++nt) {
    float gv = g[nt * 16 + m], bv = bb[nt * 16 + m];
    #pragma unroll
    for (int r = 0; r < 4; ++r) {
      float o = (y[nt][r] - mean[r]) * sig[r] * gv + bv;
      out[(size_t)(r0 + q * 4 + r) * H + nt * 16 + m] = (ushort_t)f2bf_bits(o);
    }
  }
}

__global__ __launch_bounds__(256)
void sage_stay_mfma(const ushort_t* __restrict__ agg2, const ushort_t* __restrict__ agg3,
                    const ushort_t* __restrict__ x,
                    const ushort_t* __restrict__ fWl2, const ushort_t* __restrict__ fWr2,
                    const ushort_t* __restrict__ fWl3, const ushort_t* __restrict__ fWr3,
                    const float* __restrict__ bl2, const float* __restrict__ bl3,
                    const float* __restrict__ g, const float* __restrict__ bb,
                    ushort_t* __restrict__ out, int N) {
  const int PLANE = 4096;
  const int wid = threadIdx.x >> 6, lane = threadIdx.x & 63;
  const int r0 = blockIdx.x * 64 + wid * 16;
  if (r0 >= N) return;
  const int m = lane & 15, q = lane >> 4;
  const ushort_t* a2p = agg2 + (size_t)(r0 + m) * H + q * 8;
  const ushort_t* a3p = agg3 + (size_t)(r0 + m) * H + q * 8;
  const ushort_t* xp  = x    + (size_t)(r0 + m) * H + q * 8;
  bf16x8 A2[2], A3[2], X[2];
  A2[0] = ld_frag(a2p); A2[1] = ld_frag(a2p + 32);
  A3[0] = ld_frag(a3p); A3[1] = ld_frag(a3p + 32);
  X[0]  = ld_frag(xp);  X[1]  = ld_frag(xp + 32);
  f32x4 c2[4] = {{0,0,0,0},{0,0,0,0},{0,0,0,0},{0,0,0,0}};
  f32x4 c3[4] = {{0,0,0,0},{0,0,0,0},{0,0,0,0},{0,0,0,0}};
  #pragma unroll
  for (int nt = 0; nt < 4; ++nt) {
    #pragma unroll
    for (int ks = 0; ks < 2; ++ks) {
      const size_t fo = ((size_t)(nt * 2 + ks) * 64 + lane) * 8;
      bf16x8 bh = ld_frag(fWl2 + fo), blo = ld_frag(fWl2 + PLANE + fo);
      c2[nt] = MFMA16(A2[ks], bh, c2[nt]);
      c2[nt] = MFMA16(A2[ks], blo, c2[nt]);
      bh = ld_frag(fWr2 + fo); blo = ld_frag(fWr2 + PLANE + fo);
      c2[nt] = MFMA16(X[ks], bh, c2[nt]);
      c2[nt] = MFMA16(X[ks], blo, c2[nt]);
      bh = ld_frag(fWl3 + fo); blo = ld_frag(fWl3 + PLANE + fo);
      c3[nt] = MFMA16(A3[ks], bh, c3[nt]);
      c3[nt] = MFMA16(A3[ks], blo, c3[nt]);
      bh = ld_frag(fWr3 + fo); blo = ld_frag(fWr3 + PLANE + fo);
      c3[nt] = MFMA16(X[ks], bh, c3[nt]);
      c3[nt] = MFMA16(X[ks], blo, c3[nt]);
    }
  }
  float n2s[4] = {0,0,0,0}, n3s[4] = {0,0,0,0};
  #pragma unroll
  for (int nt = 0; nt < 4; ++nt) {
    float b2 = bl2[nt * 16 + m], b3 = bl3[nt * 16 + m];
    #pragma unroll
    for (int r = 0; r < 4; ++r) {
      c2[nt][r] += b2;
      c3[nt][r] += b3;
      n2s[r] = fmaf(c2[nt][r], c2[nt][r], n2s[r]);
      n3s[r] = fmaf(c3[nt][r], c3[nt][r], n3s[r]);
    }
  }
  #pragma unroll
  for (int off = 1; off < 16; off <<= 1)
    #pragma unroll
    for (int r = 0; r < 4; ++r) {
      n2s[r] += __shfl_xor(n2s[r], off);
      n3s[r] += __shfl_xor(n3s[r], off);
    }
  float r2v[4], r3v[4];
  #pragma unroll
  for (int r = 0; r < 4; ++r) {
    r2v[r] = 0.5f / fmaxf(sqrtf(n2s[r]), 1e-12f);
    r3v[r] = 0.5f / fmaxf(sqrtf(n3s[r]), 1e-12f);
  }
  float y[4][4];
  float s1[4] = {0,0,0,0}, s2[4] = {0,0,0,0};
  #pragma unroll
  for (int nt = 0; nt < 4; ++nt)
    #pragma unroll
    for (int r = 0; r < 4; ++r) {
      float v = fmaxf(fmaf(c2[nt][r], r2v[r], c3[nt][r] * r3v[r]), 0.0f);
      y[nt][r] = v;
      s1[r] += v;
      s2[r] = fmaf(v, v, s2[r]);
    }
  #pragma unroll
  for (int off = 1; off < 16; off <<= 1)
    #pragma unroll
    for (int r = 0; r < 4; ++r) {
      s1[r] += __shfl_xor(s1[r], off);
      s2[r] += __shfl_xor(s2[r], off);
    }
  float mean[4], sig[4];
  #pragma unroll
  for (int r = 0; r < 4; ++r) {
    mean[r] = s1[r] * (1.0f / H);
    float var = s2[r] * (1.0f / H) - mean[r] * mean[r];
    sig[r] = rsqrtf(var + 1e-5f);
  }
  #pragma unroll
  for (int nt = 0; nt < 4; ++nt) {
    float gv = g[nt * 16 + m], bv = bb[nt * 16 + m];
    #pragma unroll
    for (int r = 0; r < 4; ++r) {
      float o = (y[nt][r] - mean[r]) * sig[r] * gv + bv;
      out[(size_t)(r0 + q * 4 + r) * H + nt * 16 + m] = (ushort_t)f2bf_bits(o);
    }
  }
}

__global__ __launch_bounds__(256)
void reg_kernel(const ushort_t* __restrict__ hs, const float* __restrict__ Wreg,
                const float* __restrict__ breg, float* __restrict__ out, int N) {
  const int lane = threadIdx.x & 63;
  const int node = blockIdx.x * 4 + (threadIdx.x >> 6);
  if (node >= N) return;
  float t = bf2f(hs[(size_t)node * H + lane]) * Wreg[lane];
  t = wave_sum(t);
  if (lane == 0) out[node] = t + breg[0];
}

// -----------------------------------------------------------------------------

extern "C" void kernel_launch(void* const* d_in, const int* in_sizes, int n_in,
                              void* d_out, int out_size, void* d_ws, size_t ws_size,
                              hipStream_t stream) {
  const float* x_stay  = (const float*)d_in[0];
  const float* x_pat   = (const float*)d_in[1];
  const float* Wp_stay = (const float*)d_in[2];
  const float* bp_stay = (const float*)d_in[3];
  const float* Wp_pat  = (const float*)d_in[4];
  const float* bp_pat  = (const float*)d_in[5];
  const float* Wl      = (const float*)d_in[6];
  const float* bl      = (const float*)d_in[7];
  const float* Wr      = (const float*)d_in[8];
  const float* ln_g    = (const float*)d_in[9];
  const float* ln_b    = (const float*)d_in[10];
  const float* Wreg    = (const float*)d_in[11];
  const float* breg    = (const float*)d_in[12];
  const int* e1s = (const int*)d_in[13];
  const int* e1d = (const int*)d_in[14];
  const int* e2s = (const int*)d_in[15];
  const int* e2d = (const int*)d_in[16];
  const int* e3s = (const int*)d_in[17];
  const int* e3d = (const int*)d_in[18];
  float* out = (float*)d_out;

  const size_t S = (size_t)N_STAY * H;
  const size_t P = (size_t)N_PAT * H;

  ushort_t* hs   = (ushort_t*)d_ws;
  ushort_t* hp   = hs + S;
  ushort_t* agg1 = hp + P;
  ushort_t* agg2 = agg1 + P;
  ushort_t* agg3 = agg2 + S;
  ushort_t* fragW = agg3 + S;
  ushort_t* fWpS = fragW;                // K=128: 2*8192
  ushort_t* fWpP = fragW + 16384;        // K=64:  2*4096
  ushort_t* fWlB = fragW + 24576;        // 6 * 8192
  ushort_t* fWrB = fragW + 24576 + 49152;
  int* ib    = (int*)(fragW + 122880);
  int* off1  = ib;
  int* off2  = off1 + (N_PAT + 1);
  int* off3  = off2 + (N_STAY + 1);
  int* hist1 = off3 + (N_STAY + 1);      // hist1..hist3 contiguous
  int* hist2 = hist1 + N_PAT;
  int* hist3 = hist2 + N_STAY;
  int* csr1  = hist3 + N_STAY;
  int* csr2  = csr1 + N_EDGE;
  int* csr3  = csr2 + N_EDGE;
  int* parts = csr3 + N_EDGE;

  const int eb = (N_EDGE + 255) / 256;
  const int nb1 = (N_PAT + SCAN_CHUNK - 1) / SCAN_CHUNK;
  const int nb2 = (N_STAY + SCAN_CHUNK - 1) / SCAN_CHUNK;

  // weight preconversion (tiny)
  precvt_kernel<128><<<4, 256, 0, stream>>>(Wp_stay, fWpS, 1);
  precvt_kernel<64><<<2, 256, 0, stream>>>(Wp_pat, fWpP, 1);
  precvt_kernel<64><<<12, 256, 0, stream>>>(Wl, fWlB, 6);
  precvt_kernel<64><<<12, 256, 0, stream>>>(Wr, fWrB, 6);

  // CSR builds, merged
  hipMemsetAsync(hist1, 0, (size_t)(N_PAT + 2 * N_STAY) * sizeof(int), stream);
  hist3_kernel<<<3 * eb, 256, 0, stream>>>(e1d, e2d, e3d, hist1, hist2, hist3, eb);
  scan_block_totals<<<nb1, 256, 0, stream>>>(hist1, N_PAT, parts + 0);
  scan_block_totals<<<nb2, 256, 0, stream>>>(hist2, N_STAY, parts + 64);
  scan_block_totals<<<nb2, 256, 0, stream>>>(hist3, N_STAY, parts + 128);
  scan_partials<<<1, 64, 0, stream>>>(parts + 0, nb1);
  scan_partials<<<1, 64, 0, stream>>>(parts + 64, nb2);
  scan_partials<<<1, 64, 0, stream>>>(parts + 128, nb2);
  scan_final<<<nb1, 256, 0, stream>>>(hist1, N_PAT, parts + 0, off1, hist1, N_EDGE);
  scan_final<<<nb2, 256, 0, stream>>>(hist2, N_STAY, parts + 64, off2, hist2, N_EDGE);
  scan_final<<<nb2, 256, 0, stream>>>(hist3, N_STAY, parts + 128, off3, hist3, N_EDGE);
  reorder3_kernel<<<3 * eb, 256, 0, stream>>>(e1s, e1d, e2s, e2d, e3s, e3d,
                                              hist1, hist2, hist3, csr1, csr2, csr3, eb);

  // input projections
  proj_mfma<128><<<(N_STAY + 63) / 64, 256, 0, stream>>>(x_stay, fWpS, bp_stay, hs, N_STAY);
  proj_mfma<64><<<(N_PAT + 63) / 64, 256, 0, stream>>>(x_pat, fWpP, bp_pat, hp, N_PAT);

  const int AGG_S = (N_STAY * 64 + 255) / 256;
  const int AGG_P = (N_PAT * 64 + 255) / 256;

  for (int l = 0; l < 2; ++l) {
    ushort_t* fWl0 = fWlB + (size_t)(l * 3 + 0) * 8192;
    ushort_t* fWl1 = fWlB + (size_t)(l * 3 + 1) * 8192;
    ushort_t* fWl2 = fWlB + (size_t)(l * 3 + 2) * 8192;
    ushort_t* fWr0 = fWrB + (size_t)(l * 3 + 0) * 8192;
    ushort_t* fWr1 = fWrB + (size_t)(l * 3 + 1) * 8192;
    ushort_t* fWr2 = fWrB + (size_t)(l * 3 + 2) * 8192;
    const float* bl0 = bl + (size_t)(l * 3 + 0) * H;
    const float* bl1 = bl + (size_t)(l * 3 + 1) * H;
    const float* bl2 = bl + (size_t)(l * 3 + 2) * H;
    const float* g  = ln_g + (size_t)l * H;
    const float* bb = ln_b + (size_t)l * H;

    agg_kernel<<<AGG_P, 256, 0, stream>>>(hs, off1, csr1, agg1, N_PAT);
    agg_kernel<<<AGG_S, 256, 0, stream>>>(hp, off2, csr2, agg2, N_STAY);
    agg_kernel<<<AGG_S, 256, 0, stream>>>(hs, off3, csr3, agg3, N_STAY);

    sage_pat_mfma<<<(N_PAT + 63) / 64, 256, 0, stream>>>(
        agg1, hp, fWl0, fWr0, bl0, g, bb, hp, N_PAT);
    sage_stay_mfma<<<(N_STAY + 63) / 64, 256, 0, stream>>>(
        agg2, agg3, hs, fWl1, fWr1, fWl2, fWr2, bl1, bl2, g, bb, hs, N_STAY);
  }

  reg_kernel<<<(N_STAY + 3) / 4, 256, 0, stream>>>(hs, Wreg, breg, out, N_STAY);
}